// Round 2
// baseline (228.083 us; speedup 1.0000x reference)
//
#include <hip/hip_runtime.h>
#include <hip/hip_bf16.h>
#include <math.h>

#define F_IN   256
#define F_OUT  128
#define ALPHA  0.2f

#define BM 64
#define BK 64

// ---------------------------------------------------------------------------
// GEMM: H = A @ W  (A [M,256] row-major, W [256,128] row-major), fused with
// s_src = H @ a[:128], s_dst = H @ a[128:]
// Block: 256 threads, tile 64 rows x 128 cols (full width). Each thread: 4x8.
// ---------------------------------------------------------------------------
__global__ __launch_bounds__(256) void gemm_fused_kernel(
    const float* __restrict__ A, const float* __restrict__ W,
    const float* __restrict__ avec,
    float* __restrict__ H, float* __restrict__ s_src, float* __restrict__ s_dst,
    int M) {
  __shared__ float As[BM][BK + 4];   // +4 pad: float4-aligned rows, breaks bank conflict
  __shared__ float Bs[BK][F_OUT];

  const int tid = threadIdx.x;
  const int tx = tid & 15;          // 0..15 -> column group
  const int ty = tid >> 4;          // 0..15 -> row group
  const int row0 = blockIdx.x * BM;

  float acc[4][8] = {};

  for (int kt = 0; kt < F_IN; kt += BK) {
    // Load A tile: 64x64 floats = 1024 float4, 4 per thread
#pragma unroll
    for (int u = 0; u < 4; ++u) {
      int f4 = tid + u * 256;            // 0..1023
      int r  = f4 >> 4;                  // 16 float4 per row
      int c4 = (f4 & 15) << 2;
      float4 val = make_float4(0.f, 0.f, 0.f, 0.f);
      int gr = row0 + r;
      if (gr < M) val = *(const float4*)&A[(size_t)gr * F_IN + kt + c4];
      *(float4*)&As[r][c4] = val;
    }
    // Load B tile: 64x128 floats = 2048 float4, 8 per thread
#pragma unroll
    for (int u = 0; u < 8; ++u) {
      int f4 = tid + u * 256;            // 0..2047
      int r  = f4 >> 5;                  // 32 float4 per row
      int c4 = (f4 & 31) << 2;
      *(float4*)&Bs[r][c4] = *(const float4*)&W[(size_t)(kt + r) * F_OUT + c4];
    }
    __syncthreads();

#pragma unroll 16
    for (int k = 0; k < BK; ++k) {
      float av[4];
#pragma unroll
      for (int i = 0; i < 4; ++i) av[i] = As[ty * 4 + i][k];
      float4 b0 = *(float4*)&Bs[k][tx * 4];
      float4 b1 = *(float4*)&Bs[k][64 + tx * 4];
#pragma unroll
      for (int i = 0; i < 4; ++i) {
        acc[i][0] += av[i] * b0.x;
        acc[i][1] += av[i] * b0.y;
        acc[i][2] += av[i] * b0.z;
        acc[i][3] += av[i] * b0.w;
        acc[i][4] += av[i] * b1.x;
        acc[i][5] += av[i] * b1.y;
        acc[i][6] += av[i] * b1.z;
        acc[i][7] += av[i] * b1.w;
      }
    }
    __syncthreads();
  }

  // attention projection coefficients for this thread's columns
  float a1lo[4], a1hi[4], a2lo[4], a2hi[4];
#pragma unroll
  for (int jj = 0; jj < 4; ++jj) {
    a1lo[jj] = avec[tx * 4 + jj];
    a1hi[jj] = avec[64 + tx * 4 + jj];
    a2lo[jj] = avec[F_OUT + tx * 4 + jj];
    a2hi[jj] = avec[F_OUT + 64 + tx * 4 + jj];
  }

#pragma unroll
  for (int i = 0; i < 4; ++i) {
    float s1 = 0.f, s2 = 0.f;
#pragma unroll
    for (int jj = 0; jj < 4; ++jj) {
      s1 += acc[i][jj] * a1lo[jj] + acc[i][4 + jj] * a1hi[jj];
      s2 += acc[i][jj] * a2lo[jj] + acc[i][4 + jj] * a2hi[jj];
    }
    // reduce across the 16 tx lanes (masks < 16 stay within the ty-group)
#pragma unroll
    for (int mask = 1; mask < 16; mask <<= 1) {
      s1 += __shfl_xor(s1, mask);
      s2 += __shfl_xor(s2, mask);
    }
    int gr = row0 + ty * 4 + i;
    if (gr < M) {
      *(float4*)&H[(size_t)gr * F_OUT + tx * 4] =
          make_float4(acc[i][0], acc[i][1], acc[i][2], acc[i][3]);
      *(float4*)&H[(size_t)gr * F_OUT + 64 + tx * 4] =
          make_float4(acc[i][4], acc[i][5], acc[i][6], acc[i][7]);
      if (tx == 0) { s_src[gr] = s1; s_dst[gr] = s2; }
    }
  }
}

// ---------------------------------------------------------------------------
// CSR build
// ---------------------------------------------------------------------------
__global__ void hist_kernel(const int* __restrict__ src, int* __restrict__ deg, int E) {
  int e = blockIdx.x * blockDim.x + threadIdx.x;
  if (e < E) atomicAdd(&deg[src[e]], 1);
}

__global__ void block_sums_kernel(const int* __restrict__ deg, int* __restrict__ bs, int N) {
  int i = blockIdx.x * 256 + threadIdx.x;
  int v = (i < N) ? deg[i] : 0;
  int lane = threadIdx.x & 63, w = threadIdx.x >> 6;
#pragma unroll
  for (int d = 32; d >= 1; d >>= 1) v += __shfl_down(v, d);
  __shared__ int wsum[4];
  if (lane == 0) wsum[w] = v;
  __syncthreads();
  if (threadIdx.x == 0) bs[blockIdx.x] = wsum[0] + wsum[1] + wsum[2] + wsum[3];
}

// exclusive scan in place, n <= 256, single block of 256
__global__ void scan_blocksums_kernel(int* __restrict__ bs, int n) {
  int tid = threadIdx.x;
  int v = (tid < n) ? bs[tid] : 0;
  int lane = tid & 63, w = tid >> 6;
  int iv = v;
#pragma unroll
  for (int d = 1; d < 64; d <<= 1) {
    int t = __shfl_up(iv, d);
    if (lane >= d) iv += t;
  }
  __shared__ int wsum[4];
  if (lane == 63) wsum[w] = iv;
  __syncthreads();
  int off = 0;
  for (int x = 0; x < w; ++x) off += wsum[x];
  int excl = off + iv - v;
  if (tid < n) bs[tid] = excl;
}

__global__ void scan_deg_kernel(const int* __restrict__ deg, const int* __restrict__ bsum,
                                int* __restrict__ rowptr, int N, int E) {
  int i = blockIdx.x * 256 + threadIdx.x;
  int v = (i < N) ? deg[i] : 0;
  int lane = threadIdx.x & 63, w = threadIdx.x >> 6;
  int iv = v;
#pragma unroll
  for (int d = 1; d < 64; d <<= 1) {
    int t = __shfl_up(iv, d);
    if (lane >= d) iv += t;
  }
  __shared__ int wsum[4];
  if (lane == 63) wsum[w] = iv;
  __syncthreads();
  int off = bsum[blockIdx.x];
  for (int x = 0; x < w; ++x) off += wsum[x];
  int excl = off + iv - v;
  if (i < N) rowptr[i] = excl;
  if (i == N - 1) rowptr[N] = E;
}

__global__ void scatter_kernel(const int* __restrict__ src, const int* __restrict__ dst,
                               const int* __restrict__ rowptr, int* __restrict__ cursor,
                               int* __restrict__ colidx, int E) {
  int e = blockIdx.x * blockDim.x + threadIdx.x;
  if (e < E) {
    int s = src[e];
    int pos = atomicAdd(&cursor[s], 1);
    colidx[rowptr[s] + pos] = dst[e];
  }
}

// ---------------------------------------------------------------------------
// Per-node aggregation: one wave per node, online softmax, float2 gathers.
// ---------------------------------------------------------------------------
__global__ __launch_bounds__(64) void aggregate_kernel(
    const float* __restrict__ H, const float* __restrict__ s_src,
    const float* __restrict__ s_dst, const int* __restrict__ rowptr,
    const int* __restrict__ colidx, float* __restrict__ out) {
  int i = blockIdx.x;
  int lane = threadIdx.x;
  int beg = rowptr[i], end = rowptr[i + 1];
  float ssrc = s_src[i];
  float m = -INFINITY;
  float denom = 0.f;
  float2 acc = make_float2(0.f, 0.f);
  const float2* H2 = (const float2*)H;
  for (int k = beg; k < end; ++k) {
    int j = colidx[k];
    float e = ssrc + s_dst[j];
    e = (e > 0.f) ? e : ALPHA * e;
    float mn = fmaxf(m, e);
    float scale = __expf(m - mn);   // first iter: exp(-inf)=0
    float w = __expf(e - mn);
    denom = denom * scale + w;
    float2 hv = H2[(size_t)j * 64 + lane];
    acc.x = acc.x * scale + w * hv.x;
    acc.y = acc.y * scale + w * hv.y;
    m = mn;
  }
  float inv = (denom > 0.f) ? 1.f / denom : 0.f;
  float o0 = acc.x * inv, o1 = acc.y * inv;
  o0 = (o0 > 0.f) ? o0 : __expf(o0) - 1.f;   // ELU
  o1 = (o1 > 0.f) ? o1 : __expf(o1) - 1.f;
  ((float2*)out)[(size_t)i * 64 + lane] = make_float2(o0, o1);
}

// ---------------------------------------------------------------------------
extern "C" void kernel_launch(void* const* d_in, const int* in_sizes, int n_in,
                              void* d_out, int out_size, void* d_ws, size_t ws_size,
                              hipStream_t stream) {
  const float* x    = (const float*)d_in[0];
  const float* W    = (const float*)d_in[1];
  const float* avec = (const float*)d_in[2];
  const int*   edge = (const int*)d_in[3];

  const int M = in_sizes[0] / F_IN;   // 50000
  const int E = in_sizes[3] / 2;      // 800000
  const int* src = edge;
  const int* dst = edge + E;
  float* out = (float*)d_out;

  char* ws = (char*)d_ws;
  float* H      = (float*)ws;  ws += (size_t)M * F_OUT * sizeof(float);
  float* s_src  = (float*)ws;  ws += (size_t)M * sizeof(float);
  float* s_dst  = (float*)ws;  ws += (size_t)M * sizeof(float);
  int*   deg    = (int*)ws;    ws += (size_t)M * sizeof(int);
  int*   cursor = (int*)ws;    ws += (size_t)M * sizeof(int);
  int*   rowptr = (int*)ws;    ws += (size_t)(M + 1) * sizeof(int);
  int*   colidx = (int*)ws;    ws += (size_t)E * sizeof(int);
  int*   bsums  = (int*)ws;

  const int NS = (M + 255) / 256;

  // zero deg + cursor (contiguous)
  hipMemsetAsync(deg, 0, (size_t)2 * M * sizeof(int), stream);

  gemm_fused_kernel<<<(M + BM - 1) / BM, 256, 0, stream>>>(x, W, avec, H, s_src, s_dst, M);
  hist_kernel<<<(E + 255) / 256, 256, 0, stream>>>(src, deg, E);
  block_sums_kernel<<<NS, 256, 0, stream>>>(deg, bsums, M);
  scan_blocksums_kernel<<<1, 256, 0, stream>>>(bsums, NS);
  scan_deg_kernel<<<NS, 256, 0, stream>>>(deg, bsums, rowptr, M, E);
  scatter_kernel<<<(E + 255) / 256, 256, 0, stream>>>(src, dst, rowptr, cursor, colidx, E);
  aggregate_kernel<<<M, 64, 0, stream>>>(H, s_src, s_dst, rowptr, colidx, out);
}

// Round 3
// 210.418 us; speedup vs baseline: 1.0840x; 1.0840x over previous
//
#include <hip/hip_runtime.h>
#include <hip/hip_bf16.h>
#include <math.h>

#define F_IN   256
#define F_OUT  128
#define ALPHA  0.2f
#define TM     64       // GEMM row tile

typedef __attribute__((ext_vector_type(8))) short s16x8;
typedef __attribute__((ext_vector_type(4))) float f32x4;

__device__ __forceinline__ ushort f2bf(float f) {
  __hip_bfloat16 h = __float2bfloat16(f);
  return *reinterpret_cast<ushort*>(&h);
}

// ---------------------------------------------------------------------------
// Pack W [256][128] fp32 -> Wf bf16 in B-fragment order:
//   Wf[(kb*128 + c)*8 + j] = bf16(W[(kb*8 + j)*128 + c]),  kb=0..31, c=0..127
// B-frag load then becomes: lane l reads 16B at (kb0+(l>>4))*128 + c0+(l&15),
// i.e. 4 contiguous 256B segments per wave instruction.
// ---------------------------------------------------------------------------
__global__ __launch_bounds__(256) void pack_w_kernel(
    const float* __restrict__ W, ushort* __restrict__ Wf) {
  int idx = blockIdx.x * 256 + threadIdx.x;   // 4096 fragments-of-8
  int kb = idx >> 7, c = idx & 127;
  union { s16x8 v; ushort u[8]; } t;
#pragma unroll
  for (int j = 0; j < 8; ++j) t.u[j] = f2bf(W[(kb * 8 + j) * F_OUT + c]);
  *(s16x8*)&Wf[(size_t)idx * 8] = t.v;
}

// ---------------------------------------------------------------------------
// MFMA GEMM: Hb[M,128]bf16 = bf16(X[M,256]) @ Wf, fused s_src/s_dst epilogue.
// 64-row tile, 256 threads = 4 waves; wave w owns rows w*16..w*16+15, all
// 128 cols (8 col-frags). X staged to LDS in A-frag order with XOR swizzle.
// A-frag layout (16x16x32): lane l holds A[row=l&15][k=(l>>4)*8+j].
// C/D layout: col=l&15, row=(l>>4)*4+q  [m89-verified].
// ---------------------------------------------------------------------------
__global__ __launch_bounds__(256) void gemm_mfma_kernel(
    const float* __restrict__ X, const ushort* __restrict__ Wf,
    const float* __restrict__ avec,
    ushort* __restrict__ Hb, float* __restrict__ s_src, float* __restrict__ s_dst,
    int M) {
  __shared__ __align__(16) char Xs[TM * 256 * 2];   // 32 KB, frag-order bf16
  const int tid = threadIdx.x;
  const int l = tid & 63;
  const int w = tid >> 6;
  const int row0 = blockIdx.x * TM;

  // Stage: 64 rows x 32 kblocks; thread -> (r, kb), coalesced 32B fp32 reads.
  // LDS byte addr for frag elem (rb,kb,rr): rb*8192 + kb*256 + rr*16, then
  // XOR-swizzle ^((kb&7)<<4) -> conflict-free writes (rr fixed, kb varies)
  // AND reads (kb fixed-ish, rr varies).
#pragma unroll
  for (int it = 0; it < 8; ++it) {
    int idx = it * 256 + tid;          // 0..2047
    int r = idx >> 5, kb = idx & 31;
    f32x4 v0 = {0.f, 0.f, 0.f, 0.f}, v1 = {0.f, 0.f, 0.f, 0.f};
    if (row0 + r < M) {
      const f32x4* p = (const f32x4*)&X[(size_t)(row0 + r) * F_IN + kb * 8];
      v0 = p[0]; v1 = p[1];
    }
    union { s16x8 v; ushort u[8]; } t;
    t.u[0] = f2bf(v0[0]); t.u[1] = f2bf(v0[1]); t.u[2] = f2bf(v0[2]); t.u[3] = f2bf(v0[3]);
    t.u[4] = f2bf(v1[0]); t.u[5] = f2bf(v1[1]); t.u[6] = f2bf(v1[2]); t.u[7] = f2bf(v1[3]);
    int byte = ((r >> 4) * 8192) + kb * 256 + (r & 15) * 16;
    byte ^= (kb & 7) << 4;
    *(s16x8*)(Xs + byte) = t.v;
  }
  __syncthreads();

  f32x4 acc[8] = {};   // 8 col-frags x 4 fp32
#pragma unroll
  for (int ks = 0; ks < 8; ++ks) {
    int kb = ks * 4 + (l >> 4);
    int ab = w * 8192 + kb * 256 + (l & 15) * 16;
    ab ^= (kb & 7) << 4;
    s16x8 af = *(const s16x8*)(Xs + ab);
    const s16x8* bp = (const s16x8*)&Wf[(size_t)(kb * F_OUT + (l & 15)) * 8];
#pragma unroll
    for (int j = 0; j < 8; ++j) {
      s16x8 bfr = bp[j * 16];   // col group j*16
      acc[j] = __builtin_amdgcn_mfma_f32_16x16x32_bf16(af, bfr, acc[j], 0, 0, 0);
    }
  }

  // s_src/s_dst epilogue: lane holds col l&15 (x8 col-frags), rows (l>>4)*4+q.
  float s1[4] = {0.f, 0.f, 0.f, 0.f}, s2[4] = {0.f, 0.f, 0.f, 0.f};
#pragma unroll
  for (int j = 0; j < 8; ++j) {
    float a1c = avec[j * 16 + (l & 15)];
    float a2c = avec[F_OUT + j * 16 + (l & 15)];
#pragma unroll
    for (int q = 0; q < 4; ++q) { s1[q] += acc[j][q] * a1c; s2[q] += acc[j][q] * a2c; }
  }
#pragma unroll
  for (int mask = 1; mask < 16; mask <<= 1) {
#pragma unroll
    for (int q = 0; q < 4; ++q) {
      s1[q] += __shfl_xor(s1[q], mask);
      s2[q] += __shfl_xor(s2[q], mask);
    }
  }
  if ((l & 15) == 0) {
#pragma unroll
    for (int q = 0; q < 4; ++q) {
      int r = row0 + w * 16 + (l >> 4) * 4 + q;
      if (r < M) { s_src[r] = s1[q]; s_dst[r] = s2[q]; }
    }
  }

  // H store (bf16): pair adjacent cols across lanes l, l^1 -> 4B stores.
  const int colbase = l & 15;
  const int rbase = w * 16 + (l >> 4) * 4;
#pragma unroll
  for (int j = 0; j < 8; ++j) {
#pragma unroll
    for (int q = 0; q < 4; ++q) {
      uint hv = f2bf(acc[j][q]);
      uint other = __shfl_xor(hv, 1);
      if ((l & 1) == 0) {
        int r = row0 + rbase + q;
        if (r < M) {
          int c = j * 16 + colbase;   // even
          *(uint*)((char*)Hb + (size_t)r * 256 + c * 2) = hv | (other << 16);
        }
      }
    }
  }
}

// ---------------------------------------------------------------------------
// CSR build
// ---------------------------------------------------------------------------
__global__ void hist_kernel(const int* __restrict__ src, int* __restrict__ deg, int E) {
  int e = blockIdx.x * blockDim.x + threadIdx.x;
  if (e < E) atomicAdd(&deg[src[e]], 1);
}

__global__ void block_sums_kernel(const int* __restrict__ deg, int* __restrict__ bs, int N) {
  int i = blockIdx.x * 256 + threadIdx.x;
  int v = (i < N) ? deg[i] : 0;
  int lane = threadIdx.x & 63, w = threadIdx.x >> 6;
#pragma unroll
  for (int d = 32; d >= 1; d >>= 1) v += __shfl_down(v, d);
  __shared__ int wsum[4];
  if (lane == 0) wsum[w] = v;
  __syncthreads();
  if (threadIdx.x == 0) bs[blockIdx.x] = wsum[0] + wsum[1] + wsum[2] + wsum[3];
}

__global__ void scan_blocksums_kernel(int* __restrict__ bs, int n) {
  int tid = threadIdx.x;
  int v = (tid < n) ? bs[tid] : 0;
  int lane = tid & 63, w = tid >> 6;
  int iv = v;
#pragma unroll
  for (int d = 1; d < 64; d <<= 1) {
    int t = __shfl_up(iv, d);
    if (lane >= d) iv += t;
  }
  __shared__ int wsum[4];
  if (lane == 63) wsum[w] = iv;
  __syncthreads();
  int off = 0;
  for (int x = 0; x < w; ++x) off += wsum[x];
  int excl = off + iv - v;
  if (tid < n) bs[tid] = excl;
}

__global__ void scan_deg_kernel(const int* __restrict__ deg, const int* __restrict__ bsum,
                                int* __restrict__ rowptr, int N, int E) {
  int i = blockIdx.x * 256 + threadIdx.x;
  int v = (i < N) ? deg[i] : 0;
  int lane = threadIdx.x & 63, w = threadIdx.x >> 6;
  int iv = v;
#pragma unroll
  for (int d = 1; d < 64; d <<= 1) {
    int t = __shfl_up(iv, d);
    if (lane >= d) iv += t;
  }
  __shared__ int wsum[4];
  if (lane == 63) wsum[w] = iv;
  __syncthreads();
  int off = bsum[blockIdx.x];
  for (int x = 0; x < w; ++x) off += wsum[x];
  int excl = off + iv - v;
  if (i < N) rowptr[i] = excl;
  if (i == N - 1) rowptr[N] = E;
}

__global__ void scatter_kernel(const int* __restrict__ src, const int* __restrict__ dst,
                               const int* __restrict__ rowptr, int* __restrict__ cursor,
                               int* __restrict__ colidx, int E) {
  int e = blockIdx.x * blockDim.x + threadIdx.x;
  if (e < E) {
    int s = src[e];
    int pos = atomicAdd(&cursor[s], 1);
    colidx[rowptr[s] + pos] = dst[e];
  }
}

// ---------------------------------------------------------------------------
// Aggregation: 4 nodes per 256-thread block (one wave per node), online
// softmax, bf16 H gather (4B/lane = 256B/edge coalesced).
// ---------------------------------------------------------------------------
__global__ __launch_bounds__(256) void aggregate_kernel(
    const ushort* __restrict__ Hb, const float* __restrict__ s_src,
    const float* __restrict__ s_dst, const int* __restrict__ rowptr,
    const int* __restrict__ colidx, float* __restrict__ out, int M) {
  int node = blockIdx.x * 4 + (threadIdx.x >> 6);
  int l = threadIdx.x & 63;
  if (node >= M) return;
  int beg = rowptr[node], end = rowptr[node + 1];
  float ssrc = s_src[node];
  float m = -INFINITY, denom = 0.f, ax = 0.f, ay = 0.f;
  for (int k = beg; k < end; ++k) {
    int j = colidx[k];
    float e = ssrc + s_dst[j];
    e = (e > 0.f) ? e : ALPHA * e;
    float mn = fmaxf(m, e);
    float sc = __expf(m - mn);     // first iter: exp(-inf) = 0
    float wt = __expf(e - mn);
    uint u = *(const uint*)((const char*)Hb + (size_t)j * 256 + l * 4);
    float h0 = __uint_as_float(u << 16);
    float h1 = __uint_as_float(u & 0xffff0000u);
    denom = denom * sc + wt;
    ax = ax * sc + wt * h0;
    ay = ay * sc + wt * h1;
    m = mn;
  }
  float inv = (denom > 0.f) ? 1.f / denom : 0.f;
  float o0 = ax * inv, o1 = ay * inv;
  o0 = (o0 > 0.f) ? o0 : __expf(o0) - 1.f;   // ELU
  o1 = (o1 > 0.f) ? o1 : __expf(o1) - 1.f;
  ((float2*)out)[(size_t)node * 64 + l] = make_float2(o0, o1);
}

// ---------------------------------------------------------------------------
extern "C" void kernel_launch(void* const* d_in, const int* in_sizes, int n_in,
                              void* d_out, int out_size, void* d_ws, size_t ws_size,
                              hipStream_t stream) {
  const float* x    = (const float*)d_in[0];
  const float* W    = (const float*)d_in[1];
  const float* avec = (const float*)d_in[2];
  const int*   edge = (const int*)d_in[3];

  const int M = in_sizes[0] / F_IN;   // 50000
  const int E = in_sizes[3] / 2;      // 800000
  const int* src = edge;
  const int* dst = edge + E;
  float* out = (float*)d_out;

  char* ws = (char*)d_ws;
  ushort* Hb    = (ushort*)ws; ws += (size_t)M * F_OUT * sizeof(ushort);
  ushort* Wf    = (ushort*)ws; ws += (size_t)32 * F_OUT * 8 * sizeof(ushort);
  float* s_src  = (float*)ws;  ws += (size_t)M * sizeof(float);
  float* s_dst  = (float*)ws;  ws += (size_t)M * sizeof(float);
  int*   deg    = (int*)ws;    ws += (size_t)M * sizeof(int);
  int*   cursor = (int*)ws;    ws += (size_t)M * sizeof(int);
  int*   rowptr = (int*)ws;    ws += (size_t)(M + 1) * sizeof(int);
  int*   colidx = (int*)ws;    ws += (size_t)E * sizeof(int);
  int*   bsums  = (int*)ws;

  const int NS = (M + 255) / 256;

  hipMemsetAsync(deg, 0, (size_t)2 * M * sizeof(int), stream);   // deg + cursor

  pack_w_kernel<<<16, 256, 0, stream>>>(W, Wf);
  gemm_mfma_kernel<<<(M + TM - 1) / TM, 256, 0, stream>>>(x, Wf, avec, Hb, s_src, s_dst, M);
  hist_kernel<<<(E + 255) / 256, 256, 0, stream>>>(src, deg, E);
  block_sums_kernel<<<NS, 256, 0, stream>>>(deg, bsums, M);
  scan_blocksums_kernel<<<1, 256, 0, stream>>>(bsums, NS);
  scan_deg_kernel<<<NS, 256, 0, stream>>>(deg, bsums, rowptr, M, E);
  scatter_kernel<<<(E + 255) / 256, 256, 0, stream>>>(src, dst, rowptr, cursor, colidx, E);
  aggregate_kernel<<<(M + 3) / 4, 256, 0, stream>>>(Hb, s_src, s_dst, rowptr, colidx, out, M);
}

// Round 5
// 172.164 us; speedup vs baseline: 1.3248x; 1.2222x over previous
//
#include <hip/hip_runtime.h>
#include <hip/hip_bf16.h>
#include <math.h>

#define F_IN   256
#define F_OUT  128
#define ALPHA  0.2f
#define TM     64       // GEMM row tile

typedef __attribute__((ext_vector_type(8))) short s16x8;
typedef __attribute__((ext_vector_type(4))) float f32x4;

__device__ __forceinline__ ushort f2bf(float f) {
  __hip_bfloat16 h = __float2bfloat16(f);
  return *reinterpret_cast<ushort*>(&h);
}
__device__ __forceinline__ uint pk2bf(float lo, float hi) {
  return (uint)f2bf(lo) | ((uint)f2bf(hi) << 16);
}

// ---------------------------------------------------------------------------
// Pack W [256][128] fp32 -> Wf bf16 in B-fragment order:
//   Wf[(kb*128 + c)*8 + j] = bf16(W[(kb*8 + j)*128 + c]),  kb=0..31, c=0..127
// ---------------------------------------------------------------------------
__global__ __launch_bounds__(256) void pack_w_kernel(
    const float* __restrict__ W, ushort* __restrict__ Wf) {
  int idx = blockIdx.x * 256 + threadIdx.x;   // 4096 fragments-of-8
  int kb = idx >> 7, c = idx & 127;
  union { s16x8 v; ushort u[8]; } t;
#pragma unroll
  for (int j = 0; j < 8; ++j) t.u[j] = f2bf(W[(kb * 8 + j) * F_OUT + c]);
  *(s16x8*)&Wf[(size_t)idx * 8] = t.v;
}

// ---------------------------------------------------------------------------
// wa1 = W @ a[:128], wa2 = W @ a[128:] packed as a 16-col B-frag tile Wfs:
//   col 0 = wa1, col 1 = wa2, cols 2..15 = 0.
//   Wfs[(kb*16 + cc)*8 + j8] = bf16 of B[kb*8+j8][128+cc]
// One block of 256 threads, thread = k row of W.
// ---------------------------------------------------------------------------
__global__ __launch_bounds__(256) void pack_wa_kernel(
    const float* __restrict__ W, const float* __restrict__ avec,
    ushort* __restrict__ Wfs) {
  int k = threadIdx.x;   // 0..255
  float s1 = 0.f, s2 = 0.f;
  for (int c = 0; c < F_OUT; ++c) {
    float wv = W[k * F_OUT + c];
    s1 += wv * avec[c];
    s2 += wv * avec[F_OUT + c];
  }
  int kb = k >> 3, j8 = k & 7;
  ushort b1 = f2bf(s1), b2 = f2bf(s2);
#pragma unroll
  for (int cc = 0; cc < 16; ++cc) {
    ushort v = (cc == 0) ? b1 : (cc == 1) ? b2 : (ushort)0;
    Wfs[((size_t)kb * 16 + cc) * 8 + j8] = v;
  }
}

// ---------------------------------------------------------------------------
// MFMA GEMM: Hb32[M][64] u32 = packed bf16 cols (l, l+64) of H = bf16(X) @ W.
// 64-row tile, 256 threads = 4 waves. Wave w owns col-frags j=w and j=w+4
// (cols 16w..16w+15 and 64+16w..64+16w+15) over all 64 rows.
// B-frags preloaded to registers (16 loads/wave, hoisted). A staged in LDS
// (frag order, XOR swizzle). s_src/s_dst via 9th B-frag (wa cols) on wave 0.
// A-frag: lane l holds A[row=l&15][k=(l>>4)*8+t]. C/D: col=l&15, row=(l>>4)*4+q.
// ---------------------------------------------------------------------------
__global__ __launch_bounds__(256) void gemm_mfma_kernel(
    const float* __restrict__ X, const ushort* __restrict__ Wf,
    const ushort* __restrict__ Wfs,
    uint* __restrict__ Hb32, float* __restrict__ s_src, float* __restrict__ s_dst,
    int M) {
  __shared__ __align__(16) char Xs[TM * 256 * 2];   // 32 KB, frag-order bf16
  const int tid = threadIdx.x;
  const int l = tid & 63;
  const int w = tid >> 6;
  const int lc = l & 15;
  const int lg = l >> 4;
  const int row0 = blockIdx.x * TM;

  // Preload B fragments for this wave's two col-frags (issue before staging).
  s16x8 bfr0[8], bfr1[8];
#pragma unroll
  for (int ks = 0; ks < 8; ++ks) {
    int kb = ks * 4 + lg;
    bfr0[ks] = *(const s16x8*)&Wf[((size_t)kb * F_OUT + w * 16 + lc) * 8];
    bfr1[ks] = *(const s16x8*)&Wf[((size_t)kb * F_OUT + 64 + w * 16 + lc) * 8];
  }

  // Stage X tile: fp32 -> bf16, frag order, XOR swizzle ^((kb&7)<<4).
#pragma unroll
  for (int it = 0; it < 8; ++it) {
    int idx = it * 256 + tid;          // 0..2047 -> (r, kb)
    int r = idx >> 5, kb = idx & 31;
    f32x4 v0 = {0.f, 0.f, 0.f, 0.f}, v1 = {0.f, 0.f, 0.f, 0.f};
    if (row0 + r < M) {
      const f32x4* p = (const f32x4*)&X[(size_t)(row0 + r) * F_IN + kb * 8];
      v0 = p[0]; v1 = p[1];
    }
    union { s16x8 v; ushort u[8]; } t;
    t.u[0] = f2bf(v0[0]); t.u[1] = f2bf(v0[1]); t.u[2] = f2bf(v0[2]); t.u[3] = f2bf(v0[3]);
    t.u[4] = f2bf(v1[0]); t.u[5] = f2bf(v1[1]); t.u[6] = f2bf(v1[2]); t.u[7] = f2bf(v1[3]);
    int byte = ((r >> 4) * 8192) + kb * 256 + (r & 15) * 16;
    byte ^= (kb & 7) << 4;
    *(s16x8*)(Xs + byte) = t.v;
  }
  __syncthreads();

  f32x4 acc0[4] = {}, acc1[4] = {}, accS[4] = {};
#pragma unroll
  for (int ks = 0; ks < 8; ++ks) {
    int kb = ks * 4 + lg;
    int ab = kb * 256 + lc * 16;
    ab ^= (kb & 7) << 4;
    s16x8 bS;
    if (w == 0) bS = *(const s16x8*)&Wfs[((size_t)kb * 16 + lc) * 8];
#pragma unroll
    for (int rf = 0; rf < 4; ++rf) {
      s16x8 af = *(const s16x8*)(Xs + rf * 8192 + ab);
      acc0[rf] = __builtin_amdgcn_mfma_f32_16x16x32_bf16(af, bfr0[ks], acc0[rf], 0, 0, 0);
      acc1[rf] = __builtin_amdgcn_mfma_f32_16x16x32_bf16(af, bfr1[ks], acc1[rf], 0, 0, 0);
      if (w == 0)
        accS[rf] = __builtin_amdgcn_mfma_f32_16x16x32_bf16(af, bS, accS[rf], 0, 0, 0);
    }
  }

  // Hb store: u32 slot s = w*16+lc holds cols (s, s+64) as (lo, hi) bf16.
#pragma unroll
  for (int rf = 0; rf < 4; ++rf) {
#pragma unroll
    for (int q = 0; q < 4; ++q) {
      int rg = row0 + rf * 16 + lg * 4 + q;
      if (rg < M)
        Hb32[(size_t)rg * 64 + w * 16 + lc] = pk2bf(acc0[rf][q], acc1[rf][q]);
    }
  }

  // s_src (col 128 -> lc==0) / s_dst (col 129 -> lc==1) straight from accS.
  if (w == 0 && lc < 2) {
    float* sout = (lc == 0) ? s_src : s_dst;
#pragma unroll
    for (int rf = 0; rf < 4; ++rf) {
#pragma unroll
      for (int q = 0; q < 4; ++q) {
        int rg = row0 + rf * 16 + lg * 4 + q;
        if (rg < M) sout[rg] = accS[rf][q];
      }
    }
  }
}

// ---------------------------------------------------------------------------
// CSR build
// ---------------------------------------------------------------------------
__global__ void hist_kernel(const int* __restrict__ src, int* __restrict__ deg, int E) {
  int e = blockIdx.x * blockDim.x + threadIdx.x;
  if (e < E) atomicAdd(&deg[src[e]], 1);
}

__global__ void block_sums_kernel(const int* __restrict__ deg, int* __restrict__ bs, int N) {
  int i = blockIdx.x * 256 + threadIdx.x;
  int v = (i < N) ? deg[i] : 0;
  int lane = threadIdx.x & 63, w = threadIdx.x >> 6;
#pragma unroll
  for (int d = 32; d >= 1; d >>= 1) v += __shfl_down(v, d);
  __shared__ int wsum[4];
  if (lane == 0) wsum[w] = v;
  __syncthreads();
  if (threadIdx.x == 0) bs[blockIdx.x] = wsum[0] + wsum[1] + wsum[2] + wsum[3];
}

__global__ void scan_blocksums_kernel(int* __restrict__ bs, int n) {
  int tid = threadIdx.x;
  int v = (tid < n) ? bs[tid] : 0;
  int lane = tid & 63, w = tid >> 6;
  int iv = v;
#pragma unroll
  for (int d = 1; d < 64; d <<= 1) {
    int t = __shfl_up(iv, d);
    if (lane >= d) iv += t;
  }
  __shared__ int wsum[4];
  if (lane == 63) wsum[w] = iv;
  __syncthreads();
  int off = 0;
  for (int x = 0; x < w; ++x) off += wsum[x];
  int excl = off + iv - v;
  if (tid < n) bs[tid] = excl;
}

__global__ void scan_deg_kernel(const int* __restrict__ deg, const int* __restrict__ bsum,
                                int* __restrict__ rowptr, int N, int E) {
  int i = blockIdx.x * 256 + threadIdx.x;
  int v = (i < N) ? deg[i] : 0;
  int lane = threadIdx.x & 63, w = threadIdx.x >> 6;
  int iv = v;
#pragma unroll
  for (int d = 1; d < 64; d <<= 1) {
    int t = __shfl_up(iv, d);
    if (lane >= d) iv += t;
  }
  __shared__ int wsum[4];
  if (lane == 63) wsum[w] = iv;
  __syncthreads();
  int off = bsum[blockIdx.x];
  for (int x = 0; x < w; ++x) off += wsum[x];
  int excl = off + iv - v;
  if (i < N) rowptr[i] = excl;
  if (i == N - 1) rowptr[N] = E;
}

__global__ void scatter_kernel(const int* __restrict__ src, const int* __restrict__ dst,
                               const int* __restrict__ rowptr, int* __restrict__ cursor,
                               int* __restrict__ colidx, int E) {
  int e = blockIdx.x * blockDim.x + threadIdx.x;
  if (e < E) {
    int s = src[e];
    int pos = atomicAdd(&cursor[s], 1);
    colidx[rowptr[s] + pos] = dst[e];
  }
}

// ---------------------------------------------------------------------------
// Aggregation: one wave per node (4/block). Lane-parallel softmax per <=64-edge
// chunk (one rescale per chunk), then tight gather loop with shfl-broadcast
// (j, w) pairs, 2-way unrolled. Lane l owns cols (l, l+64) per Hb32 layout.
// ---------------------------------------------------------------------------
__global__ __launch_bounds__(256) void aggregate_kernel(
    const uint* __restrict__ H32, const float* __restrict__ s_src,
    const float* __restrict__ s_dst, const int* __restrict__ rowptr,
    const int* __restrict__ colidx, float* __restrict__ out, int M) {
  int node = blockIdx.x * 4 + (threadIdx.x >> 6);
  int l = threadIdx.x & 63;
  if (node >= M) return;
  int beg = rowptr[node], end = rowptr[node + 1];
  float ssrc = s_src[node];
  float m = -INFINITY, denom = 0.f, aLo = 0.f, aHi = 0.f;

  for (int base = beg; base < end; base += 64) {
    int cnt = end - base; if (cnt > 64) cnt = 64;
    int jv = 0; float ev = -INFINITY;
    if (l < cnt) {
      jv = colidx[base + l];
      float e = ssrc + s_dst[jv];
      ev = (e > 0.f) ? e : ALPHA * e;
    }
    // chunk max
    float cm = ev;
#pragma unroll
    for (int mask = 1; mask < 64; mask <<= 1) cm = fmaxf(cm, __shfl_xor(cm, mask));
    float mn = fmaxf(m, cm);
    float wv = (l < cnt) ? __expf(ev - mn) : 0.f;
    float sw = wv;
#pragma unroll
    for (int mask = 1; mask < 64; mask <<= 1) sw += __shfl_xor(sw, mask);
    float resc = __expf(m - mn);   // first chunk: exp(-inf) = 0
    denom = denom * resc + sw;
    aLo *= resc; aHi *= resc;
    m = mn;

    int k = 0;
    for (; k + 2 <= cnt; k += 2) {
      int j0 = __shfl(jv, k), j1 = __shfl(jv, k + 1);
      float w0 = __shfl(wv, k), w1 = __shfl(wv, k + 1);
      uint u0 = H32[((uint)j0 << 6) + l];
      uint u1 = H32[((uint)j1 << 6) + l];
      aLo += w0 * __uint_as_float(u0 << 16) + w1 * __uint_as_float(u1 << 16);
      aHi += w0 * __uint_as_float(u0 & 0xffff0000u) + w1 * __uint_as_float(u1 & 0xffff0000u);
    }
    if (k < cnt) {
      int j0 = __shfl(jv, k); float w0 = __shfl(wv, k);
      uint u0 = H32[((uint)j0 << 6) + l];
      aLo += w0 * __uint_as_float(u0 << 16);
      aHi += w0 * __uint_as_float(u0 & 0xffff0000u);
    }
  }

  float inv = (denom > 0.f) ? 1.f / denom : 0.f;
  float o0 = aLo * inv, o1 = aHi * inv;
  o0 = (o0 > 0.f) ? o0 : __expf(o0) - 1.f;   // ELU
  o1 = (o1 > 0.f) ? o1 : __expf(o1) - 1.f;
  out[(size_t)node * 128 + l] = o0;
  out[(size_t)node * 128 + 64 + l] = o1;
}

// ---------------------------------------------------------------------------
extern "C" void kernel_launch(void* const* d_in, const int* in_sizes, int n_in,
                              void* d_out, int out_size, void* d_ws, size_t ws_size,
                              hipStream_t stream) {
  const float* x    = (const float*)d_in[0];
  const float* W    = (const float*)d_in[1];
  const float* avec = (const float*)d_in[2];
  const int*   edge = (const int*)d_in[3];

  const int M = in_sizes[0] / F_IN;   // 50000
  const int E = in_sizes[3] / 2;      // 800000
  const int* src = edge;
  const int* dst = edge + E;
  float* out = (float*)d_out;

  char* ws = (char*)d_ws;
  uint*   Hb32  = (uint*)ws;   ws += (size_t)M * 64 * sizeof(uint);
  ushort* Wf    = (ushort*)ws; ws += (size_t)32 * F_OUT * 8 * sizeof(ushort);
  ushort* Wfs   = (ushort*)ws; ws += (size_t)32 * 16 * 8 * sizeof(ushort);
  float* s_src  = (float*)ws;  ws += (size_t)M * sizeof(float);
  float* s_dst  = (float*)ws;  ws += (size_t)M * sizeof(float);
  int*   deg    = (int*)ws;    ws += (size_t)M * sizeof(int);
  int*   cursor = (int*)ws;    ws += (size_t)M * sizeof(int);
  int*   rowptr = (int*)ws;    ws += (size_t)(M + 1) * sizeof(int);
  int*   colidx = (int*)ws;    ws += (size_t)E * sizeof(int);
  int*   bsums  = (int*)ws;

  const int NS = (M + 255) / 256;

  hipMemsetAsync(deg, 0, (size_t)2 * M * sizeof(int), stream);   // deg + cursor

  pack_w_kernel<<<16, 256, 0, stream>>>(W, Wf);
  pack_wa_kernel<<<1, 256, 0, stream>>>(W, avec, Wfs);
  gemm_mfma_kernel<<<(M + TM - 1) / TM, 256, 0, stream>>>(x, Wf, Wfs, Hb32, s_src, s_dst, M);
  hist_kernel<<<(E + 255) / 256, 256, 0, stream>>>(src, deg, E);
  block_sums_kernel<<<NS, 256, 0, stream>>>(deg, bsums, M);
  scan_blocksums_kernel<<<1, 256, 0, stream>>>(bsums, NS);
  scan_deg_kernel<<<NS, 256, 0, stream>>>(deg, bsums, rowptr, M, E);
  scatter_kernel<<<(E + 255) / 256, 256, 0, stream>>>(src, dst, rowptr, cursor, colidx, E);
  aggregate_kernel<<<(M + 3) / 4, 256, 0, stream>>>(Hb32, s_src, s_dst, rowptr, colidx, out, M);
}

// Round 6
// 163.509 us; speedup vs baseline: 1.3949x; 1.0529x over previous
//
#include <hip/hip_runtime.h>
#include <hip/hip_bf16.h>
#include <math.h>

#define F_IN   256
#define F_OUT  128
#define ALPHA  0.2f
#define TM     64       // GEMM row tile
#define SWEEPS 8        // scatter sweeps (one per XCD, blockIdx&7 heuristic)
#define CHUNK  4096     // edges per scatter block

typedef __attribute__((ext_vector_type(8))) short s16x8;
typedef __attribute__((ext_vector_type(4))) float f32x4;

__device__ __forceinline__ ushort f2bf(float f) {
  __hip_bfloat16 h = __float2bfloat16(f);
  return *reinterpret_cast<ushort*>(&h);
}
__device__ __forceinline__ uint pk2bf(float lo, float hi) {
  return (uint)f2bf(lo) | ((uint)f2bf(hi) << 16);
}

// ---------------------------------------------------------------------------
// Pack W [256][128] fp32 -> Wf bf16 in B-fragment order:
//   Wf[(kb*128 + c)*8 + j] = bf16(W[(kb*8 + j)*128 + c]),  kb=0..31, c=0..127
// ---------------------------------------------------------------------------
__global__ __launch_bounds__(256) void pack_w_kernel(
    const float* __restrict__ W, ushort* __restrict__ Wf) {
  int idx = blockIdx.x * 256 + threadIdx.x;   // 4096 fragments-of-8
  int kb = idx >> 7, c = idx & 127;
  union { s16x8 v; ushort u[8]; } t;
#pragma unroll
  for (int j = 0; j < 8; ++j) t.u[j] = f2bf(W[(kb * 8 + j) * F_OUT + c]);
  *(s16x8*)&Wf[(size_t)idx * 8] = t.v;
}

// ---------------------------------------------------------------------------
// wa1 = W @ a[:128], wa2 = W @ a[128:] packed as a 16-col B-frag tile Wfs:
//   col 0 = wa1, col 1 = wa2, cols 2..15 = 0.
// ---------------------------------------------------------------------------
__global__ __launch_bounds__(256) void pack_wa_kernel(
    const float* __restrict__ W, const float* __restrict__ avec,
    ushort* __restrict__ Wfs) {
  int k = threadIdx.x;   // 0..255
  float s1 = 0.f, s2 = 0.f;
  for (int c = 0; c < F_OUT; ++c) {
    float wv = W[k * F_OUT + c];
    s1 += wv * avec[c];
    s2 += wv * avec[F_OUT + c];
  }
  int kb = k >> 3, j8 = k & 7;
  ushort b1 = f2bf(s1), b2 = f2bf(s2);
#pragma unroll
  for (int cc = 0; cc < 16; ++cc) {
    ushort v = (cc == 0) ? b1 : (cc == 1) ? b2 : (ushort)0;
    Wfs[((size_t)kb * 16 + cc) * 8 + j8] = v;
  }
}

// ---------------------------------------------------------------------------
// MFMA GEMM: Hb32[M][64] u32 = packed bf16 cols (l, l+64) of H = bf16(X) @ W.
// 64-row tile, 256 threads = 4 waves; wave w owns col-frags j=w, j=w+4.
// B-frags preloaded to registers; A staged in LDS (frag order, XOR swizzle).
// s_src/s_dst via 9th B-frag (wa cols) on wave 0.
// ---------------------------------------------------------------------------
__global__ __launch_bounds__(256) void gemm_mfma_kernel(
    const float* __restrict__ X, const ushort* __restrict__ Wf,
    const ushort* __restrict__ Wfs,
    uint* __restrict__ Hb32, float* __restrict__ s_src, float* __restrict__ s_dst,
    int M) {
  __shared__ __align__(16) char Xs[TM * 256 * 2];   // 32 KB, frag-order bf16
  const int tid = threadIdx.x;
  const int l = tid & 63;
  const int w = tid >> 6;
  const int lc = l & 15;
  const int lg = l >> 4;
  const int row0 = blockIdx.x * TM;

  // Preload B fragments for this wave's two col-frags.
  s16x8 bfr0[8], bfr1[8];
#pragma unroll
  for (int ks = 0; ks < 8; ++ks) {
    int kb = ks * 4 + lg;
    bfr0[ks] = *(const s16x8*)&Wf[((size_t)kb * F_OUT + w * 16 + lc) * 8];
    bfr1[ks] = *(const s16x8*)&Wf[((size_t)kb * F_OUT + 64 + w * 16 + lc) * 8];
  }

  // Stage X tile: fp32 -> bf16, frag order, XOR swizzle ^((kb&7)<<4).
#pragma unroll
  for (int it = 0; it < 8; ++it) {
    int idx = it * 256 + tid;          // 0..2047 -> (r, kb)
    int r = idx >> 5, kb = idx & 31;
    f32x4 v0 = {0.f, 0.f, 0.f, 0.f}, v1 = {0.f, 0.f, 0.f, 0.f};
    if (row0 + r < M) {
      const f32x4* p = (const f32x4*)&X[(size_t)(row0 + r) * F_IN + kb * 8];
      v0 = p[0]; v1 = p[1];
    }
    union { s16x8 v; ushort u[8]; } t;
    t.u[0] = f2bf(v0[0]); t.u[1] = f2bf(v0[1]); t.u[2] = f2bf(v0[2]); t.u[3] = f2bf(v0[3]);
    t.u[4] = f2bf(v1[0]); t.u[5] = f2bf(v1[1]); t.u[6] = f2bf(v1[2]); t.u[7] = f2bf(v1[3]);
    int byte = ((r >> 4) * 8192) + kb * 256 + (r & 15) * 16;
    byte ^= (kb & 7) << 4;
    *(s16x8*)(Xs + byte) = t.v;
  }
  __syncthreads();

  f32x4 acc0[4] = {}, acc1[4] = {}, accS[4] = {};
#pragma unroll
  for (int ks = 0; ks < 8; ++ks) {
    int kb = ks * 4 + lg;
    int ab = kb * 256 + lc * 16;
    ab ^= (kb & 7) << 4;
    s16x8 bS;
    if (w == 0) bS = *(const s16x8*)&Wfs[((size_t)kb * 16 + lc) * 8];
#pragma unroll
    for (int rf = 0; rf < 4; ++rf) {
      s16x8 af = *(const s16x8*)(Xs + rf * 8192 + ab);
      acc0[rf] = __builtin_amdgcn_mfma_f32_16x16x32_bf16(af, bfr0[ks], acc0[rf], 0, 0, 0);
      acc1[rf] = __builtin_amdgcn_mfma_f32_16x16x32_bf16(af, bfr1[ks], acc1[rf], 0, 0, 0);
      if (w == 0)
        accS[rf] = __builtin_amdgcn_mfma_f32_16x16x32_bf16(af, bS, accS[rf], 0, 0, 0);
    }
  }

  // Hb store: u32 slot s = w*16+lc holds cols (s, s+64) as (lo, hi) bf16.
#pragma unroll
  for (int rf = 0; rf < 4; ++rf) {
#pragma unroll
    for (int q = 0; q < 4; ++q) {
      int rg = row0 + rf * 16 + lg * 4 + q;
      if (rg < M)
        Hb32[(size_t)rg * 64 + w * 16 + lc] = pk2bf(acc0[rf][q], acc1[rf][q]);
    }
  }

  // s_src (lc==0) / s_dst (lc==1) straight from accS.
  if (w == 0 && lc < 2) {
    float* sout = (lc == 0) ? s_src : s_dst;
#pragma unroll
    for (int rf = 0; rf < 4; ++rf) {
#pragma unroll
      for (int q = 0; q < 4; ++q) {
        int rg = row0 + rf * 16 + lg * 4 + q;
        if (rg < M) sout[rg] = accS[rf][q];
      }
    }
  }
}

// ---------------------------------------------------------------------------
// CSR build
// ---------------------------------------------------------------------------
__global__ void hist_kernel(const int* __restrict__ src, int* __restrict__ deg, int E) {
  int e = blockIdx.x * blockDim.x + threadIdx.x;
  if (e < E) atomicAdd(&deg[src[e]], 1);
}

__global__ void block_sums_kernel(const int* __restrict__ deg, int* __restrict__ bs, int N) {
  int i = blockIdx.x * 256 + threadIdx.x;
  int v = (i < N) ? deg[i] : 0;
  int lane = threadIdx.x & 63, w = threadIdx.x >> 6;
#pragma unroll
  for (int d = 32; d >= 1; d >>= 1) v += __shfl_down(v, d);
  __shared__ int wsum[4];
  if (lane == 0) wsum[w] = v;
  __syncthreads();
  if (threadIdx.x == 0) bs[blockIdx.x] = wsum[0] + wsum[1] + wsum[2] + wsum[3];
}

__global__ void scan_blocksums_kernel(int* __restrict__ bs, int n) {
  int tid = threadIdx.x;
  int v = (tid < n) ? bs[tid] : 0;
  int lane = tid & 63, w = tid >> 6;
  int iv = v;
#pragma unroll
  for (int d = 1; d < 64; d <<= 1) {
    int t = __shfl_up(iv, d);
    if (lane >= d) iv += t;
  }
  __shared__ int wsum[4];
  if (lane == 63) wsum[w] = iv;
  __syncthreads();
  int off = 0;
  for (int x = 0; x < w; ++x) off += wsum[x];
  int excl = off + iv - v;
  if (tid < n) bs[tid] = excl;
}

__global__ void scan_deg_kernel(const int* __restrict__ deg, const int* __restrict__ bsum,
                                int* __restrict__ rowptr, int N, int E) {
  int i = blockIdx.x * 256 + threadIdx.x;
  int v = (i < N) ? deg[i] : 0;
  int lane = threadIdx.x & 63, w = threadIdx.x >> 6;
  int iv = v;
#pragma unroll
  for (int d = 1; d < 64; d <<= 1) {
    int t = __shfl_up(iv, d);
    if (lane >= d) iv += t;
  }
  __shared__ int wsum[4];
  if (lane == 63) wsum[w] = iv;
  __syncthreads();
  int off = bsum[blockIdx.x];
  for (int x = 0; x < w; ++x) off += wsum[x];
  int excl = off + iv - v;
  if (i < N) rowptr[i] = excl;
  if (i == N - 1) rowptr[N] = E;
}

// ---------------------------------------------------------------------------
// Sweep-partitioned scatter: sweep = blockIdx&7 -> src range [lo,hi).
// All writes of a sweep land in a ~M/8-node colidx window (L2-resident, one
// XCD via round-robin block->XCD heuristic) -> full-line writebacks instead
// of 64B/write amplification. Edge list re-read 8x from L2/L3 (cheap).
// ---------------------------------------------------------------------------
__global__ __launch_bounds__(256) void scatter_sweep_kernel(
    const int* __restrict__ src, const int* __restrict__ dst,
    const int* __restrict__ rowptr, int* __restrict__ cursor,
    int* __restrict__ colidx, int E, int nps) {
  int sweep = blockIdx.x & (SWEEPS - 1);
  int chunk = blockIdx.x >> 3;
  int lo = sweep * nps, hi = lo + nps;
  int base = chunk * CHUNK;
  int end = base + CHUNK; if (end > E) end = E;
  for (int k = base + threadIdx.x; k < end; k += 256) {
    int s = src[k];
    if (s >= lo && s < hi) {
      int pos = atomicAdd(&cursor[s], 1);
      colidx[rowptr[s] + pos] = dst[k];
    }
  }
}

// ---------------------------------------------------------------------------
// Aggregation: one wave per node (4/block). Lane-parallel softmax per <=64-edge
// chunk, then shfl-broadcast gather loop. Lane l owns cols (l, l+64).
// ---------------------------------------------------------------------------
__global__ __launch_bounds__(256) void aggregate_kernel(
    const uint* __restrict__ H32, const float* __restrict__ s_src,
    const float* __restrict__ s_dst, const int* __restrict__ rowptr,
    const int* __restrict__ colidx, float* __restrict__ out, int M) {
  int node = blockIdx.x * 4 + (threadIdx.x >> 6);
  int l = threadIdx.x & 63;
  if (node >= M) return;
  int beg = rowptr[node], end = rowptr[node + 1];
  float ssrc = s_src[node];
  float m = -INFINITY, denom = 0.f, aLo = 0.f, aHi = 0.f;

  for (int base = beg; base < end; base += 64) {
    int cnt = end - base; if (cnt > 64) cnt = 64;
    int jv = 0; float ev = -INFINITY;
    if (l < cnt) {
      jv = colidx[base + l];
      float e = ssrc + s_dst[jv];
      ev = (e > 0.f) ? e : ALPHA * e;
    }
    float cm = ev;
#pragma unroll
    for (int mask = 1; mask < 64; mask <<= 1) cm = fmaxf(cm, __shfl_xor(cm, mask));
    float mn = fmaxf(m, cm);
    float wv = (l < cnt) ? __expf(ev - mn) : 0.f;
    float sw = wv;
#pragma unroll
    for (int mask = 1; mask < 64; mask <<= 1) sw += __shfl_xor(sw, mask);
    float resc = __expf(m - mn);   // first chunk: exp(-inf) = 0
    denom = denom * resc + sw;
    aLo *= resc; aHi *= resc;
    m = mn;

    int k = 0;
    for (; k + 2 <= cnt; k += 2) {
      int j0 = __shfl(jv, k), j1 = __shfl(jv, k + 1);
      float w0 = __shfl(wv, k), w1 = __shfl(wv, k + 1);
      uint u0 = H32[((uint)j0 << 6) + l];
      uint u1 = H32[((uint)j1 << 6) + l];
      aLo += w0 * __uint_as_float(u0 << 16) + w1 * __uint_as_float(u1 << 16);
      aHi += w0 * __uint_as_float(u0 & 0xffff0000u) + w1 * __uint_as_float(u1 & 0xffff0000u);
    }
    if (k < cnt) {
      int j0 = __shfl(jv, k); float w0 = __shfl(wv, k);
      uint u0 = H32[((uint)j0 << 6) + l];
      aLo += w0 * __uint_as_float(u0 << 16);
      aHi += w0 * __uint_as_float(u0 & 0xffff0000u);
    }
  }

  float inv = (denom > 0.f) ? 1.f / denom : 0.f;
  float o0 = aLo * inv, o1 = aHi * inv;
  o0 = (o0 > 0.f) ? o0 : __expf(o0) - 1.f;   // ELU
  o1 = (o1 > 0.f) ? o1 : __expf(o1) - 1.f;
  out[(size_t)node * 128 + l] = o0;
  out[(size_t)node * 128 + 64 + l] = o1;
}

// ---------------------------------------------------------------------------
extern "C" void kernel_launch(void* const* d_in, const int* in_sizes, int n_in,
                              void* d_out, int out_size, void* d_ws, size_t ws_size,
                              hipStream_t stream) {
  const float* x    = (const float*)d_in[0];
  const float* W    = (const float*)d_in[1];
  const float* avec = (const float*)d_in[2];
  const int*   edge = (const int*)d_in[3];

  const int M = in_sizes[0] / F_IN;   // 50000
  const int E = in_sizes[3] / 2;      // 800000
  const int* src = edge;
  const int* dst = edge + E;
  float* out = (float*)d_out;

  char* ws = (char*)d_ws;
  uint*   Hb32  = (uint*)ws;   ws += (size_t)M * 64 * sizeof(uint);
  ushort* Wf    = (ushort*)ws; ws += (size_t)32 * F_OUT * 8 * sizeof(ushort);
  ushort* Wfs   = (ushort*)ws; ws += (size_t)32 * 16 * 8 * sizeof(ushort);
  float* s_src  = (float*)ws;  ws += (size_t)M * sizeof(float);
  float* s_dst  = (float*)ws;  ws += (size_t)M * sizeof(float);
  int*   deg    = (int*)ws;    ws += (size_t)M * sizeof(int);
  int*   cursor = (int*)ws;    ws += (size_t)M * sizeof(int);
  int*   rowptr = (int*)ws;    ws += (size_t)(M + 1) * sizeof(int);
  int*   colidx = (int*)ws;    ws += (size_t)E * sizeof(int);
  int*   bsums  = (int*)ws;

  const int NS = (M + 255) / 256;
  const int nps = (M + SWEEPS - 1) / SWEEPS;           // nodes per sweep
  const int nchunks = (E + CHUNK - 1) / CHUNK;

  hipMemsetAsync(deg, 0, (size_t)2 * M * sizeof(int), stream);   // deg + cursor

  pack_w_kernel<<<16, 256, 0, stream>>>(W, Wf);
  pack_wa_kernel<<<1, 256, 0, stream>>>(W, avec, Wfs);
  gemm_mfma_kernel<<<(M + TM - 1) / TM, 256, 0, stream>>>(x, Wf, Wfs, Hb32, s_src, s_dst, M);
  hist_kernel<<<(E + 255) / 256, 256, 0, stream>>>(src, deg, E);
  block_sums_kernel<<<NS, 256, 0, stream>>>(deg, bsums, M);
  scan_blocksums_kernel<<<1, 256, 0, stream>>>(bsums, NS);
  scan_deg_kernel<<<NS, 256, 0, stream>>>(deg, bsums, rowptr, M, E);
  scatter_sweep_kernel<<<nchunks * SWEEPS, 256, 0, stream>>>(src, dst, rowptr, cursor, colidx, E, nps);
  aggregate_kernel<<<(M + 3) / 4, 256, 0, stream>>>(Hb32, s_src, s_dst, rowptr, colidx, out, M);
}

// Round 7
// 156.556 us; speedup vs baseline: 1.4569x; 1.0444x over previous
//
#include <hip/hip_runtime.h>
#include <hip/hip_bf16.h>
#include <math.h>

#define F_IN   256
#define F_OUT  128
#define ALPHA  0.2f
#define TM     64       // GEMM row tile
#define SWEEPS 8        // scatter sweeps (one per XCD, blockIdx&7 heuristic)
#define CHUNK  4096     // edges per scatter block

typedef __attribute__((ext_vector_type(8))) short s16x8;
typedef __attribute__((ext_vector_type(4))) float f32x4;

__device__ __forceinline__ ushort f2bf(float f) {
  __hip_bfloat16 h = __float2bfloat16(f);
  return *reinterpret_cast<ushort*>(&h);
}
__device__ __forceinline__ uint pk2bf(float lo, float hi) {
  return (uint)f2bf(lo) | ((uint)f2bf(hi) << 16);
}
__device__ __forceinline__ float bflo(uint u) { return __uint_as_float(u << 16); }
__device__ __forceinline__ float bfhi(uint u) { return __uint_as_float(u & 0xffff0000u); }

// ---------------------------------------------------------------------------
// Pack W [256][128] fp32 -> Wf bf16 in B-fragment order:
//   Wf[(kb*128 + c)*8 + j] = bf16(W[(kb*8 + j)*128 + c]),  kb=0..31, c=0..127
// ---------------------------------------------------------------------------
__global__ __launch_bounds__(256) void pack_w_kernel(
    const float* __restrict__ W, ushort* __restrict__ Wf) {
  int idx = blockIdx.x * 256 + threadIdx.x;   // 4096 fragments-of-8
  int kb = idx >> 7, c = idx & 127;
  union { s16x8 v; ushort u[8]; } t;
#pragma unroll
  for (int j = 0; j < 8; ++j) t.u[j] = f2bf(W[(kb * 8 + j) * F_OUT + c]);
  *(s16x8*)&Wf[(size_t)idx * 8] = t.v;
}

// ---------------------------------------------------------------------------
// wa1 = W @ a[:128], wa2 = W @ a[128:] packed as a 16-col B-frag tile Wfs:
//   col 0 = wa1, col 1 = wa2, cols 2..15 = 0.
// ---------------------------------------------------------------------------
__global__ __launch_bounds__(256) void pack_wa_kernel(
    const float* __restrict__ W, const float* __restrict__ avec,
    ushort* __restrict__ Wfs) {
  int k = threadIdx.x;   // 0..255
  float s1 = 0.f, s2 = 0.f;
  for (int c = 0; c < F_OUT; ++c) {
    float wv = W[k * F_OUT + c];
    s1 += wv * avec[c];
    s2 += wv * avec[F_OUT + c];
  }
  int kb = k >> 3, j8 = k & 7;
  ushort b1 = f2bf(s1), b2 = f2bf(s2);
#pragma unroll
  for (int cc = 0; cc < 16; ++cc) {
    ushort v = (cc == 0) ? b1 : (cc == 1) ? b2 : (ushort)0;
    Wfs[((size_t)kb * 16 + cc) * 8 + j8] = v;
  }
}

// ---------------------------------------------------------------------------
// MFMA GEMM: Hb32[M][64] u32 = packed bf16 cols (l, l+64) of H = bf16(X) @ W.
// 64-row tile, 256 threads = 4 waves; wave w owns col-frags j=w, j=w+4.
// B-frags preloaded to registers; A staged in LDS (frag order, XOR swizzle).
// s_src/s_dst via 9th B-frag (wa cols) on wave 0.
// ---------------------------------------------------------------------------
__global__ __launch_bounds__(256) void gemm_mfma_kernel(
    const float* __restrict__ X, const ushort* __restrict__ Wf,
    const ushort* __restrict__ Wfs,
    uint* __restrict__ Hb32, float* __restrict__ s_src, float* __restrict__ s_dst,
    int M) {
  __shared__ __align__(16) char Xs[TM * 256 * 2];   // 32 KB, frag-order bf16
  const int tid = threadIdx.x;
  const int l = tid & 63;
  const int w = tid >> 6;
  const int lc = l & 15;
  const int lg = l >> 4;
  const int row0 = blockIdx.x * TM;

  // Preload B fragments for this wave's two col-frags.
  s16x8 bfr0[8], bfr1[8];
#pragma unroll
  for (int ks = 0; ks < 8; ++ks) {
    int kb = ks * 4 + lg;
    bfr0[ks] = *(const s16x8*)&Wf[((size_t)kb * F_OUT + w * 16 + lc) * 8];
    bfr1[ks] = *(const s16x8*)&Wf[((size_t)kb * F_OUT + 64 + w * 16 + lc) * 8];
  }

  // Stage X tile: fp32 -> bf16, frag order, XOR swizzle ^((kb&7)<<4).
#pragma unroll
  for (int it = 0; it < 8; ++it) {
    int idx = it * 256 + tid;          // 0..2047 -> (r, kb)
    int r = idx >> 5, kb = idx & 31;
    f32x4 v0 = {0.f, 0.f, 0.f, 0.f}, v1 = {0.f, 0.f, 0.f, 0.f};
    if (row0 + r < M) {
      const f32x4* p = (const f32x4*)&X[(size_t)(row0 + r) * F_IN + kb * 8];
      v0 = p[0]; v1 = p[1];
    }
    union { s16x8 v; ushort u[8]; } t;
    t.u[0] = f2bf(v0[0]); t.u[1] = f2bf(v0[1]); t.u[2] = f2bf(v0[2]); t.u[3] = f2bf(v0[3]);
    t.u[4] = f2bf(v1[0]); t.u[5] = f2bf(v1[1]); t.u[6] = f2bf(v1[2]); t.u[7] = f2bf(v1[3]);
    int byte = ((r >> 4) * 8192) + kb * 256 + (r & 15) * 16;
    byte ^= (kb & 7) << 4;
    *(s16x8*)(Xs + byte) = t.v;
  }
  __syncthreads();

  f32x4 acc0[4] = {}, acc1[4] = {}, accS[4] = {};
#pragma unroll
  for (int ks = 0; ks < 8; ++ks) {
    int kb = ks * 4 + lg;
    int ab = kb * 256 + lc * 16;
    ab ^= (kb & 7) << 4;
    s16x8 bS;
    if (w == 0) bS = *(const s16x8*)&Wfs[((size_t)kb * 16 + lc) * 8];
#pragma unroll
    for (int rf = 0; rf < 4; ++rf) {
      s16x8 af = *(const s16x8*)(Xs + rf * 8192 + ab);
      acc0[rf] = __builtin_amdgcn_mfma_f32_16x16x32_bf16(af, bfr0[ks], acc0[rf], 0, 0, 0);
      acc1[rf] = __builtin_amdgcn_mfma_f32_16x16x32_bf16(af, bfr1[ks], acc1[rf], 0, 0, 0);
      if (w == 0)
        accS[rf] = __builtin_amdgcn_mfma_f32_16x16x32_bf16(af, bS, accS[rf], 0, 0, 0);
    }
  }

  // Hb store: u32 slot s = w*16+lc holds cols (s, s+64) as (lo, hi) bf16.
#pragma unroll
  for (int rf = 0; rf < 4; ++rf) {
#pragma unroll
    for (int q = 0; q < 4; ++q) {
      int rg = row0 + rf * 16 + lg * 4 + q;
      if (rg < M)
        Hb32[(size_t)rg * 64 + w * 16 + lc] = pk2bf(acc0[rf][q], acc1[rf][q]);
    }
  }

  // s_src (lc==0) / s_dst (lc==1) straight from accS.
  if (w == 0 && lc < 2) {
    float* sout = (lc == 0) ? s_src : s_dst;
#pragma unroll
    for (int rf = 0; rf < 4; ++rf) {
#pragma unroll
      for (int q = 0; q < 4; ++q) {
        int rg = row0 + rf * 16 + lg * 4 + q;
        if (rg < M) sout[rg] = accS[rf][q];
      }
    }
  }
}

// ---------------------------------------------------------------------------
// CSR build
// ---------------------------------------------------------------------------
__global__ void hist_kernel(const int* __restrict__ src, int* __restrict__ deg, int E) {
  int e = blockIdx.x * blockDim.x + threadIdx.x;
  if (e < E) atomicAdd(&deg[src[e]], 1);
}

__global__ void block_sums_kernel(const int* __restrict__ deg, int* __restrict__ bs, int N) {
  int i = blockIdx.x * 256 + threadIdx.x;
  int v = (i < N) ? deg[i] : 0;
  int lane = threadIdx.x & 63, w = threadIdx.x >> 6;
#pragma unroll
  for (int d = 32; d >= 1; d >>= 1) v += __shfl_down(v, d);
  __shared__ int wsum[4];
  if (lane == 0) wsum[w] = v;
  __syncthreads();
  if (threadIdx.x == 0) bs[blockIdx.x] = wsum[0] + wsum[1] + wsum[2] + wsum[3];
}

__global__ void scan_blocksums_kernel(int* __restrict__ bs, int n) {
  int tid = threadIdx.x;
  int v = (tid < n) ? bs[tid] : 0;
  int lane = tid & 63, w = tid >> 6;
  int iv = v;
#pragma unroll
  for (int d = 1; d < 64; d <<= 1) {
    int t = __shfl_up(iv, d);
    if (lane >= d) iv += t;
  }
  __shared__ int wsum[4];
  if (lane == 63) wsum[w] = iv;
  __syncthreads();
  int off = 0;
  for (int x = 0; x < w; ++x) off += wsum[x];
  int excl = off + iv - v;
  if (tid < n) bs[tid] = excl;
}

__global__ void scan_deg_kernel(const int* __restrict__ deg, const int* __restrict__ bsum,
                                int* __restrict__ rowptr, int N, int E) {
  int i = blockIdx.x * 256 + threadIdx.x;
  int v = (i < N) ? deg[i] : 0;
  int lane = threadIdx.x & 63, w = threadIdx.x >> 6;
  int iv = v;
#pragma unroll
  for (int d = 1; d < 64; d <<= 1) {
    int t = __shfl_up(iv, d);
    if (lane >= d) iv += t;
  }
  __shared__ int wsum[4];
  if (lane == 63) wsum[w] = iv;
  __syncthreads();
  int off = bsum[blockIdx.x];
  for (int x = 0; x < w; ++x) off += wsum[x];
  int excl = off + iv - v;
  if (i < N) rowptr[i] = excl;
  if (i == N - 1) rowptr[N] = E;
}

// ---------------------------------------------------------------------------
// Sweep-partitioned scatter: sweep = blockIdx&7 -> src range [lo,hi).
// ---------------------------------------------------------------------------
__global__ __launch_bounds__(256) void scatter_sweep_kernel(
    const int* __restrict__ src, const int* __restrict__ dst,
    const int* __restrict__ rowptr, int* __restrict__ cursor,
    int* __restrict__ colidx, int E, int nps) {
  int sweep = blockIdx.x & (SWEEPS - 1);
  int chunk = blockIdx.x >> 3;
  int lo = sweep * nps, hi = lo + nps;
  int base = chunk * CHUNK;
  int end = base + CHUNK; if (end > E) end = E;
  for (int k = base + threadIdx.x; k < end; k += 256) {
    int s = src[k];
    if (s >= lo && s < hi) {
      int pos = atomicAdd(&cursor[s], 1);
      colidx[rowptr[s] + pos] = dst[k];
    }
  }
}

// ---------------------------------------------------------------------------
// Aggregation v2: one wave per node (4/block). Lane-parallel softmax per
// <=64-edge chunk, then 4-edge-parallel gather: wave = 4 groups x 16 lanes,
// group g takes edge k+g, lane lc loads uint4 = slots lc*4..lc*4+3 (16B).
// Hand-unrolled x2 -> 8 edges/iter, 2 outstanding dwordx4 loads/lane.
// Final shfl_xor(16,32) group-reduce; g0 writes lo float4, g1 hi float4.
// Slot s packs cols (s, s+64) as (lo,hi) bf16 per Hb32 layout.
// ---------------------------------------------------------------------------
__global__ __launch_bounds__(256) void aggregate_kernel(
    const uint* __restrict__ H32, const float* __restrict__ s_src,
    const float* __restrict__ s_dst, const int* __restrict__ rowptr,
    const int* __restrict__ colidx, float* __restrict__ out, int M) {
  int node = blockIdx.x * 4 + (threadIdx.x >> 6);
  int l = threadIdx.x & 63;
  if (node >= M) return;
  const int g = l >> 4;       // edge group 0..3
  const int lc = l & 15;      // column lane within group
  int beg = rowptr[node], end = rowptr[node + 1];
  float ssrc = s_src[node];
  float m = -INFINITY, denom = 0.f;
  float acc[8] = {};          // slot t: acc[2t]=lo col lc*4+t, acc[2t+1]=hi col 64+lc*4+t

  for (int base = beg; base < end; base += 64) {
    int cnt = end - base; if (cnt > 64) cnt = 64;
    int jv = 0; float ev = -INFINITY;
    if (l < cnt) {
      jv = colidx[base + l];
      float e = ssrc + s_dst[jv];
      ev = (e > 0.f) ? e : ALPHA * e;
    }
    float cm = ev;
#pragma unroll
    for (int mask = 1; mask < 64; mask <<= 1) cm = fmaxf(cm, __shfl_xor(cm, mask));
    float mn = fmaxf(m, cm);
    float wv = (l < cnt) ? __expf(ev - mn) : 0.f;   // 0 for lanes >= cnt
    float sw = wv;
#pragma unroll
    for (int mask = 1; mask < 64; mask <<= 1) sw += __shfl_xor(sw, mask);
    float resc = __expf(m - mn);   // first chunk: exp(-inf) = 0
    denom = denom * resc + sw;
#pragma unroll
    for (int t = 0; t < 8; ++t) acc[t] *= resc;
    m = mn;

    // 8 edges per iteration: groups cover k+g and k+4+g. Lanes >= cnt hold
    // (jv=0, wv=0) so out-of-range edges contribute nothing (branchless).
    for (int k = 0; k < cnt; k += 8) {
      int k0 = k + g, k1 = k + 4 + g;
      int j0 = __shfl(jv, k0);
      int j1 = (k1 < 64) ? __shfl(jv, k1) : 0;
      float w0 = __shfl(wv, k0);
      float w1 = (k1 < 64) ? __shfl(wv, k1) : 0.f;
      uint4 u0 = *(const uint4*)(H32 + ((size_t)(uint)j0 << 6) + lc * 4);
      uint4 u1 = *(const uint4*)(H32 + ((size_t)(uint)j1 << 6) + lc * 4);
      acc[0] += w0 * bflo(u0.x) + w1 * bflo(u1.x);
      acc[1] += w0 * bfhi(u0.x) + w1 * bfhi(u1.x);
      acc[2] += w0 * bflo(u0.y) + w1 * bflo(u1.y);
      acc[3] += w0 * bfhi(u0.y) + w1 * bfhi(u1.y);
      acc[4] += w0 * bflo(u0.z) + w1 * bflo(u1.z);
      acc[5] += w0 * bfhi(u0.z) + w1 * bfhi(u1.z);
      acc[6] += w0 * bflo(u0.w) + w1 * bflo(u1.w);
      acc[7] += w0 * bfhi(u0.w) + w1 * bfhi(u1.w);
    }
  }

  // reduce across the 4 edge groups (lanes lc, lc+16, lc+32, lc+48)
#pragma unroll
  for (int t = 0; t < 8; ++t) {
    acc[t] += __shfl_xor(acc[t], 16);
    acc[t] += __shfl_xor(acc[t], 32);
  }
  float inv = (denom > 0.f) ? 1.f / denom : 0.f;
  if (g == 0) {
    float4 v;
    v.x = acc[0] * inv; v.y = acc[2] * inv; v.z = acc[4] * inv; v.w = acc[6] * inv;
    v.x = (v.x > 0.f) ? v.x : __expf(v.x) - 1.f;
    v.y = (v.y > 0.f) ? v.y : __expf(v.y) - 1.f;
    v.z = (v.z > 0.f) ? v.z : __expf(v.z) - 1.f;
    v.w = (v.w > 0.f) ? v.w : __expf(v.w) - 1.f;
    *(float4*)&out[(size_t)node * 128 + lc * 4] = v;
  } else if (g == 1) {
    float4 v;
    v.x = acc[1] * inv; v.y = acc[3] * inv; v.z = acc[5] * inv; v.w = acc[7] * inv;
    v.x = (v.x > 0.f) ? v.x : __expf(v.x) - 1.f;
    v.y = (v.y > 0.f) ? v.y : __expf(v.y) - 1.f;
    v.z = (v.z > 0.f) ? v.z : __expf(v.z) - 1.f;
    v.w = (v.w > 0.f) ? v.w : __expf(v.w) - 1.f;
    *(float4*)&out[(size_t)node * 128 + 64 + lc * 4] = v;
  }
}

// ---------------------------------------------------------------------------
extern "C" void kernel_launch(void* const* d_in, const int* in_sizes, int n_in,
                              void* d_out, int out_size, void* d_ws, size_t ws_size,
                              hipStream_t stream) {
  const float* x    = (const float*)d_in[0];
  const float* W    = (const float*)d_in[1];
  const float* avec = (const float*)d_in[2];
  const int*   edge = (const int*)d_in[3];

  const int M = in_sizes[0] / F_IN;   // 50000
  const int E = in_sizes[3] / 2;      // 800000
  const int* src = edge;
  const int* dst = edge + E;
  float* out = (float*)d_out;

  char* ws = (char*)d_ws;
  uint*   Hb32  = (uint*)ws;   ws += (size_t)M * 64 * sizeof(uint);
  ushort* Wf    = (ushort*)ws; ws += (size_t)32 * F_OUT * 8 * sizeof(ushort);
  ushort* Wfs   = (ushort*)ws; ws += (size_t)32 * 16 * 8 * sizeof(ushort);
  float* s_src  = (float*)ws;  ws += (size_t)M * sizeof(float);
  float* s_dst  = (float*)ws;  ws += (size_t)M * sizeof(float);
  int*   deg    = (int*)ws;    ws += (size_t)M * sizeof(int);
  int*   cursor = (int*)ws;    ws += (size_t)M * sizeof(int);
  int*   rowptr = (int*)ws;    ws += (size_t)(M + 1) * sizeof(int);
  int*   colidx = (int*)ws;    ws += (size_t)E * sizeof(int);
  int*   bsums  = (int*)ws;

  const int NS = (M + 255) / 256;
  const int nps = (M + SWEEPS - 1) / SWEEPS;           // nodes per sweep
  const int nchunks = (E + CHUNK - 1) / CHUNK;

  hipMemsetAsync(deg, 0, (size_t)2 * M * sizeof(int), stream);   // deg + cursor

  pack_w_kernel<<<16, 256, 0, stream>>>(W, Wf);
  pack_wa_kernel<<<1, 256, 0, stream>>>(W, avec, Wfs);
  gemm_mfma_kernel<<<(M + TM - 1) / TM, 256, 0, stream>>>(x, Wf, Wfs, Hb32, s_src, s_dst, M);
  hist_kernel<<<(E + 255) / 256, 256, 0, stream>>>(src, deg, E);
  block_sums_kernel<<<NS, 256, 0, stream>>>(deg, bsums, M);
  scan_blocksums_kernel<<<1, 256, 0, stream>>>(bsums, NS);
  scan_deg_kernel<<<NS, 256, 0, stream>>>(deg, bsums, rowptr, M, E);
  scatter_sweep_kernel<<<nchunks * SWEEPS, 256, 0, stream>>>(src, dst, rowptr, cursor, colidx, E, nps);
  aggregate_kernel<<<(M + 3) / 4, 256, 0, stream>>>(Hb32, s_src, s_dst, rowptr, colidx, out, M);
}

// Round 8
// 156.273 us; speedup vs baseline: 1.4595x; 1.0018x over previous
//
#include <hip/hip_runtime.h>
#include <hip/hip_bf16.h>
#include <math.h>

#define F_IN   256
#define F_OUT  128
#define ALPHA  0.2f
#define TM     64       // GEMM row tile
#define SWEEPS 8        // scatter sweeps (one per XCD, blockIdx&7 heuristic)
#define CHUNK  4096     // edges per scatter block

typedef __attribute__((ext_vector_type(8))) short s16x8;
typedef __attribute__((ext_vector_type(4))) float f32x4;

__device__ __forceinline__ ushort f2bf(float f) {
  __hip_bfloat16 h = __float2bfloat16(f);
  return *reinterpret_cast<ushort*>(&h);
}
__device__ __forceinline__ uint pk2bf(float lo, float hi) {
  return (uint)f2bf(lo) | ((uint)f2bf(hi) << 16);
}
__device__ __forceinline__ float bflo(uint u) { return __uint_as_float(u << 16); }
__device__ __forceinline__ float bfhi(uint u) { return __uint_as_float(u & 0xffff0000u); }

// ---------------------------------------------------------------------------
// Zero kernel (replaces pathologically slow runtime fillBuffer: 44us for 400KB)
// ---------------------------------------------------------------------------
__global__ __launch_bounds__(256) void zero_kernel(int4* __restrict__ p, int n4) {
  int i = blockIdx.x * 256 + threadIdx.x;
  if (i < n4) p[i] = make_int4(0, 0, 0, 0);
}

// ---------------------------------------------------------------------------
// Pack W [256][128] fp32 -> Wf bf16 in B-fragment order:
//   Wf[(kb*128 + c)*8 + j] = bf16(W[(kb*8 + j)*128 + c]),  kb=0..31, c=0..127
// ---------------------------------------------------------------------------
__global__ __launch_bounds__(256) void pack_w_kernel(
    const float* __restrict__ W, ushort* __restrict__ Wf) {
  int idx = blockIdx.x * 256 + threadIdx.x;   // 4096 fragments-of-8
  int kb = idx >> 7, c = idx & 127;
  union { s16x8 v; ushort u[8]; } t;
#pragma unroll
  for (int j = 0; j < 8; ++j) t.u[j] = f2bf(W[(kb * 8 + j) * F_OUT + c]);
  *(s16x8*)&Wf[(size_t)idx * 8] = t.v;
}

// ---------------------------------------------------------------------------
// wa1 = W @ a[:128], wa2 = W @ a[128:] packed as a 16-col B-frag tile Wfs:
//   col 0 = wa1, col 1 = wa2, cols 2..15 = 0.
// ---------------------------------------------------------------------------
__global__ __launch_bounds__(256) void pack_wa_kernel(
    const float* __restrict__ W, const float* __restrict__ avec,
    ushort* __restrict__ Wfs) {
  int k = threadIdx.x;   // 0..255
  float s1 = 0.f, s2 = 0.f;
  for (int c = 0; c < F_OUT; ++c) {
    float wv = W[k * F_OUT + c];
    s1 += wv * avec[c];
    s2 += wv * avec[F_OUT + c];
  }
  int kb = k >> 3, j8 = k & 7;
  ushort b1 = f2bf(s1), b2 = f2bf(s2);
#pragma unroll
  for (int cc = 0; cc < 16; ++cc) {
    ushort v = (cc == 0) ? b1 : (cc == 1) ? b2 : (ushort)0;
    Wfs[((size_t)kb * 16 + cc) * 8 + j8] = v;
  }
}

// ---------------------------------------------------------------------------
// MFMA GEMM: Hb32[M][64] u32 = packed bf16 cols (l, l+64) of H = bf16(X) @ W.
// 64-row tile, 256 threads = 4 waves; wave w owns col-frags j=w, j=w+4.
// B-frags preloaded to registers; A staged in LDS (frag order, XOR swizzle).
// s_src/s_dst via 9th B-frag (wa cols) on wave 0.
// ---------------------------------------------------------------------------
__global__ __launch_bounds__(256) void gemm_mfma_kernel(
    const float* __restrict__ X, const ushort* __restrict__ Wf,
    const ushort* __restrict__ Wfs,
    uint* __restrict__ Hb32, float* __restrict__ s_src, float* __restrict__ s_dst,
    int M) {
  __shared__ __align__(16) char Xs[TM * 256 * 2];   // 32 KB, frag-order bf16
  const int tid = threadIdx.x;
  const int l = tid & 63;
  const int w = tid >> 6;
  const int lc = l & 15;
  const int lg = l >> 4;
  const int row0 = blockIdx.x * TM;

  // Preload B fragments for this wave's two col-frags.
  s16x8 bfr0[8], bfr1[8];
#pragma unroll
  for (int ks = 0; ks < 8; ++ks) {
    int kb = ks * 4 + lg;
    bfr0[ks] = *(const s16x8*)&Wf[((size_t)kb * F_OUT + w * 16 + lc) * 8];
    bfr1[ks] = *(const s16x8*)&Wf[((size_t)kb * F_OUT + 64 + w * 16 + lc) * 8];
  }

  // Stage X tile: fp32 -> bf16, frag order, XOR swizzle ^((kb&7)<<4).
#pragma unroll
  for (int it = 0; it < 8; ++it) {
    int idx = it * 256 + tid;          // 0..2047 -> (r, kb)
    int r = idx >> 5, kb = idx & 31;
    f32x4 v0 = {0.f, 0.f, 0.f, 0.f}, v1 = {0.f, 0.f, 0.f, 0.f};
    if (row0 + r < M) {
      const f32x4* p = (const f32x4*)&X[(size_t)(row0 + r) * F_IN + kb * 8];
      v0 = p[0]; v1 = p[1];
    }
    union { s16x8 v; ushort u[8]; } t;
    t.u[0] = f2bf(v0[0]); t.u[1] = f2bf(v0[1]); t.u[2] = f2bf(v0[2]); t.u[3] = f2bf(v0[3]);
    t.u[4] = f2bf(v1[0]); t.u[5] = f2bf(v1[1]); t.u[6] = f2bf(v1[2]); t.u[7] = f2bf(v1[3]);
    int byte = ((r >> 4) * 8192) + kb * 256 + (r & 15) * 16;
    byte ^= (kb & 7) << 4;
    *(s16x8*)(Xs + byte) = t.v;
  }
  __syncthreads();

  f32x4 acc0[4] = {}, acc1[4] = {}, accS[4] = {};
#pragma unroll
  for (int ks = 0; ks < 8; ++ks) {
    int kb = ks * 4 + lg;
    int ab = kb * 256 + lc * 16;
    ab ^= (kb & 7) << 4;
    s16x8 bS;
    if (w == 0) bS = *(const s16x8*)&Wfs[((size_t)kb * 16 + lc) * 8];
#pragma unroll
    for (int rf = 0; rf < 4; ++rf) {
      s16x8 af = *(const s16x8*)(Xs + rf * 8192 + ab);
      acc0[rf] = __builtin_amdgcn_mfma_f32_16x16x32_bf16(af, bfr0[ks], acc0[rf], 0, 0, 0);
      acc1[rf] = __builtin_amdgcn_mfma_f32_16x16x32_bf16(af, bfr1[ks], acc1[rf], 0, 0, 0);
      if (w == 0)
        accS[rf] = __builtin_amdgcn_mfma_f32_16x16x32_bf16(af, bS, accS[rf], 0, 0, 0);
    }
  }

  // Hb store: u32 slot s = w*16+lc holds cols (s, s+64) as (lo, hi) bf16.
#pragma unroll
  for (int rf = 0; rf < 4; ++rf) {
#pragma unroll
    for (int q = 0; q < 4; ++q) {
      int rg = row0 + rf * 16 + lg * 4 + q;
      if (rg < M)
        Hb32[(size_t)rg * 64 + w * 16 + lc] = pk2bf(acc0[rf][q], acc1[rf][q]);
    }
  }

  // s_src (lc==0) / s_dst (lc==1) straight from accS.
  if (w == 0 && lc < 2) {
    float* sout = (lc == 0) ? s_src : s_dst;
#pragma unroll
    for (int rf = 0; rf < 4; ++rf) {
#pragma unroll
      for (int q = 0; q < 4; ++q) {
        int rg = row0 + rf * 16 + lg * 4 + q;
        if (rg < M) sout[rg] = accS[rf][q];
      }
    }
  }
}

// ---------------------------------------------------------------------------
// CSR build
// ---------------------------------------------------------------------------
__global__ void hist_kernel(const int* __restrict__ src, int* __restrict__ deg, int E) {
  int e = blockIdx.x * blockDim.x + threadIdx.x;
  if (e < E) atomicAdd(&deg[__builtin_nontemporal_load(src + e)], 1);
}

__global__ void block_sums_kernel(const int* __restrict__ deg, int* __restrict__ bs, int N) {
  int i = blockIdx.x * 256 + threadIdx.x;
  int v = (i < N) ? deg[i] : 0;
  int lane = threadIdx.x & 63, w = threadIdx.x >> 6;
#pragma unroll
  for (int d = 32; d >= 1; d >>= 1) v += __shfl_down(v, d);
  __shared__ int wsum[4];
  if (lane == 0) wsum[w] = v;
  __syncthreads();
  if (threadIdx.x == 0) bs[blockIdx.x] = wsum[0] + wsum[1] + wsum[2] + wsum[3];
}

__global__ void scan_blocksums_kernel(int* __restrict__ bs, int n) {
  int tid = threadIdx.x;
  int v = (tid < n) ? bs[tid] : 0;
  int lane = tid & 63, w = tid >> 6;
  int iv = v;
#pragma unroll
  for (int d = 1; d < 64; d <<= 1) {
    int t = __shfl_up(iv, d);
    if (lane >= d) iv += t;
  }
  __shared__ int wsum[4];
  if (lane == 63) wsum[w] = iv;
  __syncthreads();
  int off = 0;
  for (int x = 0; x < w; ++x) off += wsum[x];
  int excl = off + iv - v;
  if (tid < n) bs[tid] = excl;
}

// writes rowptr AND initializes cursor with the same exclusive-scan base
__global__ void scan_deg_kernel(const int* __restrict__ deg, const int* __restrict__ bsum,
                                int* __restrict__ rowptr, int* __restrict__ cursor,
                                int N, int E) {
  int i = blockIdx.x * 256 + threadIdx.x;
  int v = (i < N) ? deg[i] : 0;
  int lane = threadIdx.x & 63, w = threadIdx.x >> 6;
  int iv = v;
#pragma unroll
  for (int d = 1; d < 64; d <<= 1) {
    int t = __shfl_up(iv, d);
    if (lane >= d) iv += t;
  }
  __shared__ int wsum[4];
  if (lane == 63) wsum[w] = iv;
  __syncthreads();
  int off = bsum[blockIdx.x];
  for (int x = 0; x < w; ++x) off += wsum[x];
  int excl = off + iv - v;
  if (i < N) { rowptr[i] = excl; cursor[i] = excl; }
  if (i == N - 1) rowptr[N] = E;
}

// ---------------------------------------------------------------------------
// Sweep-partitioned scatter: sweep = blockIdx&7 -> src range [lo,hi).
// NT loads for the streaming edge list so it doesn't evict the sweep's
// L2-resident colidx window (write-combining stays effective). cursor holds
// absolute positions (seeded from rowptr by scan_deg).
// ---------------------------------------------------------------------------
__global__ __launch_bounds__(256) void scatter_sweep_kernel(
    const int* __restrict__ src, const int* __restrict__ dst,
    int* __restrict__ cursor, int* __restrict__ colidx, int E, int nps) {
  int sweep = blockIdx.x & (SWEEPS - 1);
  int chunk = blockIdx.x >> 3;
  int lo = sweep * nps, hi = lo + nps;
  int base = chunk * CHUNK;
  int end = base + CHUNK; if (end > E) end = E;
  for (int k = base + threadIdx.x; k < end; k += 256) {
    int s = __builtin_nontemporal_load(src + k);
    if (s >= lo && s < hi) {
      int pos = atomicAdd(&cursor[s], 1);
      colidx[pos] = __builtin_nontemporal_load(dst + k);
    }
  }
}

// ---------------------------------------------------------------------------
// Aggregation v2: one wave per node (4/block). Lane-parallel softmax per
// <=64-edge chunk, then 4-edge-parallel gather: wave = 4 groups x 16 lanes,
// group g takes edge k+g, lane lc loads uint4 = slots lc*4..lc*4+3 (16B).
// Hand-unrolled x2 -> 8 edges/iter. Final shfl_xor(16,32) group-reduce.
// Slot s packs cols (s, s+64) as (lo,hi) bf16 per Hb32 layout.
// ---------------------------------------------------------------------------
__global__ __launch_bounds__(256) void aggregate_kernel(
    const uint* __restrict__ H32, const float* __restrict__ s_src,
    const float* __restrict__ s_dst, const int* __restrict__ rowptr,
    const int* __restrict__ colidx, float* __restrict__ out, int M) {
  int node = blockIdx.x * 4 + (threadIdx.x >> 6);
  int l = threadIdx.x & 63;
  if (node >= M) return;
  const int g = l >> 4;       // edge group 0..3
  const int lc = l & 15;      // column lane within group
  int beg = rowptr[node], end = rowptr[node + 1];
  float ssrc = s_src[node];
  float m = -INFINITY, denom = 0.f;
  float acc[8] = {};          // slot t: acc[2t]=lo col lc*4+t, acc[2t+1]=hi col 64+lc*4+t

  for (int base = beg; base < end; base += 64) {
    int cnt = end - base; if (cnt > 64) cnt = 64;
    int jv = 0; float ev = -INFINITY;
    if (l < cnt) {
      jv = colidx[base + l];
      float e = ssrc + s_dst[jv];
      ev = (e > 0.f) ? e : ALPHA * e;
    }
    float cm = ev;
#pragma unroll
    for (int mask = 1; mask < 64; mask <<= 1) cm = fmaxf(cm, __shfl_xor(cm, mask));
    float mn = fmaxf(m, cm);
    float wv = (l < cnt) ? __expf(ev - mn) : 0.f;   // 0 for lanes >= cnt
    float sw = wv;
#pragma unroll
    for (int mask = 1; mask < 64; mask <<= 1) sw += __shfl_xor(sw, mask);
    float resc = __expf(m - mn);   // first chunk: exp(-inf) = 0
    denom = denom * resc + sw;
#pragma unroll
    for (int t = 0; t < 8; ++t) acc[t] *= resc;
    m = mn;

    // 8 edges per iteration: groups cover k+g and k+4+g. Lanes >= cnt hold
    // (jv=0, wv=0) so out-of-range edges contribute nothing (branchless).
    for (int k = 0; k < cnt; k += 8) {
      int k0 = k + g, k1 = k + 4 + g;
      int j0 = __shfl(jv, k0);
      int j1 = (k1 < 64) ? __shfl(jv, k1) : 0;
      float w0 = __shfl(wv, k0);
      float w1 = (k1 < 64) ? __shfl(wv, k1) : 0.f;
      uint4 u0 = *(const uint4*)(H32 + ((size_t)(uint)j0 << 6) + lc * 4);
      uint4 u1 = *(const uint4*)(H32 + ((size_t)(uint)j1 << 6) + lc * 4);
      acc[0] += w0 * bflo(u0.x) + w1 * bflo(u1.x);
      acc[1] += w0 * bfhi(u0.x) + w1 * bfhi(u1.x);
      acc[2] += w0 * bflo(u0.y) + w1 * bflo(u1.y);
      acc[3] += w0 * bfhi(u0.y) + w1 * bfhi(u1.y);
      acc[4] += w0 * bflo(u0.z) + w1 * bflo(u1.z);
      acc[5] += w0 * bfhi(u0.z) + w1 * bfhi(u1.z);
      acc[6] += w0 * bflo(u0.w) + w1 * bflo(u1.w);
      acc[7] += w0 * bfhi(u0.w) + w1 * bfhi(u1.w);
    }
  }

  // reduce across the 4 edge groups (lanes lc, lc+16, lc+32, lc+48)
#pragma unroll
  for (int t = 0; t < 8; ++t) {
    acc[t] += __shfl_xor(acc[t], 16);
    acc[t] += __shfl_xor(acc[t], 32);
  }
  float inv = (denom > 0.f) ? 1.f / denom : 0.f;
  if (g == 0) {
    float4 v;
    v.x = acc[0] * inv; v.y = acc[2] * inv; v.z = acc[4] * inv; v.w = acc[6] * inv;
    v.x = (v.x > 0.f) ? v.x : __expf(v.x) - 1.f;
    v.y = (v.y > 0.f) ? v.y : __expf(v.y) - 1.f;
    v.z = (v.z > 0.f) ? v.z : __expf(v.z) - 1.f;
    v.w = (v.w > 0.f) ? v.w : __expf(v.w) - 1.f;
    *(float4*)&out[(size_t)node * 128 + lc * 4] = v;
  } else if (g == 1) {
    float4 v;
    v.x = acc[1] * inv; v.y = acc[3] * inv; v.z = acc[5] * inv; v.w = acc[7] * inv;
    v.x = (v.x > 0.f) ? v.x : __expf(v.x) - 1.f;
    v.y = (v.y > 0.f) ? v.y : __expf(v.y) - 1.f;
    v.z = (v.z > 0.f) ? v.z : __expf(v.z) - 1.f;
    v.w = (v.w > 0.f) ? v.w : __expf(v.w) - 1.f;
    *(float4*)&out[(size_t)node * 128 + 64 + lc * 4] = v;
  }
}

// ---------------------------------------------------------------------------
extern "C" void kernel_launch(void* const* d_in, const int* in_sizes, int n_in,
                              void* d_out, int out_size, void* d_ws, size_t ws_size,
                              hipStream_t stream) {
  const float* x    = (const float*)d_in[0];
  const float* W    = (const float*)d_in[1];
  const float* avec = (const float*)d_in[2];
  const int*   edge = (const int*)d_in[3];

  const int M = in_sizes[0] / F_IN;   // 50000
  const int E = in_sizes[3] / 2;      // 800000
  const int* src = edge;
  const int* dst = edge + E;
  float* out = (float*)d_out;

  char* ws = (char*)d_ws;
  uint*   Hb32  = (uint*)ws;   ws += (size_t)M * 64 * sizeof(uint);
  ushort* Wf    = (ushort*)ws; ws += (size_t)32 * F_OUT * 8 * sizeof(ushort);
  ushort* Wfs   = (ushort*)ws; ws += (size_t)32 * 16 * 8 * sizeof(ushort);
  float* s_src  = (float*)ws;  ws += (size_t)M * sizeof(float);
  float* s_dst  = (float*)ws;  ws += (size_t)M * sizeof(float);
  int*   deg    = (int*)ws;    ws += (size_t)M * sizeof(int);
  int*   cursor = (int*)ws;    ws += (size_t)M * sizeof(int);
  int*   rowptr = (int*)ws;    ws += (size_t)(M + 1) * sizeof(int);
  int*   colidx = (int*)ws;    ws += (size_t)E * sizeof(int);
  int*   bsums  = (int*)ws;

  const int NS = (M + 255) / 256;
  const int nps = (M + SWEEPS - 1) / SWEEPS;           // nodes per sweep
  const int nchunks = (E + CHUNK - 1) / CHUNK;
  const int n4 = M / 4;                                // deg zero (M % 4 == 0)

  zero_kernel<<<(n4 + 255) / 256, 256, 0, stream>>>((int4*)deg, n4);
  pack_w_kernel<<<16, 256, 0, stream>>>(W, Wf);
  pack_wa_kernel<<<1, 256, 0, stream>>>(W, avec, Wfs);
  gemm_mfma_kernel<<<(M + TM - 1) / TM, 256, 0, stream>>>(x, Wf, Wfs, Hb32, s_src, s_dst, M);
  hist_kernel<<<(E + 255) / 256, 256, 0, stream>>>(src, deg, E);
  block_sums_kernel<<<NS, 256, 0, stream>>>(deg, bsums, M);
  scan_blocksums_kernel<<<1, 256, 0, stream>>>(bsums, NS);
  scan_deg_kernel<<<NS, 256, 0, stream>>>(deg, bsums, rowptr, cursor, M, E);
  scatter_sweep_kernel<<<nchunks * SWEEPS, 256, 0, stream>>>(src, dst, cursor, colidx, E, nps);
  aggregate_kernel<<<(M + 3) / 4, 256, 0, stream>>>(Hb32, s_src, s_dst, rowptr, colidx, out, M);
}

// Round 9
// 129.732 us; speedup vs baseline: 1.7581x; 1.2046x over previous
//
#include <hip/hip_runtime.h>
#include <hip/hip_bf16.h>
#include <math.h>

#define F_IN   256
#define F_OUT  128
#define ALPHA  0.2f
#define TM     64       // GEMM row tile

typedef __attribute__((ext_vector_type(8))) short s16x8;
typedef __attribute__((ext_vector_type(4))) float f32x4;

__device__ __forceinline__ ushort f2bf(float f) {
  __hip_bfloat16 h = __float2bfloat16(f);
  return *reinterpret_cast<ushort*>(&h);
}
__device__ __forceinline__ uint pk2bf(float lo, float hi) {
  return (uint)f2bf(lo) | ((uint)f2bf(hi) << 16);
}
__device__ __forceinline__ float bflo(uint u) { return __uint_as_float(u << 16); }
__device__ __forceinline__ float bfhi(uint u) { return __uint_as_float(u & 0xffff0000u); }

// ---------------------------------------------------------------------------
// Zero kernel (runtime fillBuffer was 44us for 400KB)
// ---------------------------------------------------------------------------
__global__ __launch_bounds__(256) void zero_kernel(int4* __restrict__ p, int n4) {
  int i = blockIdx.x * 256 + threadIdx.x;
  if (i < n4) p[i] = make_int4(0, 0, 0, 0);
}

// ---------------------------------------------------------------------------
// Pack W [256][128] fp32 -> Wf bf16 in B-fragment order:
//   Wf[(kb*128 + c)*8 + j] = bf16(W[(kb*8 + j)*128 + c]),  kb=0..31, c=0..127
// ---------------------------------------------------------------------------
__global__ __launch_bounds__(256) void pack_w_kernel(
    const float* __restrict__ W, ushort* __restrict__ Wf) {
  int idx = blockIdx.x * 256 + threadIdx.x;   // 4096 fragments-of-8
  int kb = idx >> 7, c = idx & 127;
  union { s16x8 v; ushort u[8]; } t;
#pragma unroll
  for (int j = 0; j < 8; ++j) t.u[j] = f2bf(W[(kb * 8 + j) * F_OUT + c]);
  *(s16x8*)&Wf[(size_t)idx * 8] = t.v;
}

// ---------------------------------------------------------------------------
// wa1 = W @ a[:128], wa2 = W @ a[128:] packed as a 16-col B-frag tile Wfs:
//   col 0 = wa1, col 1 = wa2, cols 2..15 = 0.
// ---------------------------------------------------------------------------
__global__ __launch_bounds__(256) void pack_wa_kernel(
    const float* __restrict__ W, const float* __restrict__ avec,
    ushort* __restrict__ Wfs) {
  int k = threadIdx.x;   // 0..255
  float s1 = 0.f, s2 = 0.f;
  for (int c = 0; c < F_OUT; ++c) {
    float wv = W[k * F_OUT + c];
    s1 += wv * avec[c];
    s2 += wv * avec[F_OUT + c];
  }
  int kb = k >> 3, j8 = k & 7;
  ushort b1 = f2bf(s1), b2 = f2bf(s2);
#pragma unroll
  for (int cc = 0; cc < 16; ++cc) {
    ushort v = (cc == 0) ? b1 : (cc == 1) ? b2 : (ushort)0;
    Wfs[((size_t)kb * 16 + cc) * 8 + j8] = v;
  }
}

// ---------------------------------------------------------------------------
// MFMA GEMM: Hb32[M][64] u32 = packed bf16 cols (l, l+64) of H = bf16(X) @ W.
// 64-row tile, 256 threads = 4 waves; wave w owns col-frags j=w, j=w+4.
// B-frags preloaded to registers; A staged in LDS (frag order, XOR swizzle).
// s_src/s_dst via 9th B-frag (wa cols) on wave 0.
// ---------------------------------------------------------------------------
__global__ __launch_bounds__(256) void gemm_mfma_kernel(
    const float* __restrict__ X, const ushort* __restrict__ Wf,
    const ushort* __restrict__ Wfs,
    uint* __restrict__ Hb32, float* __restrict__ s_src, float* __restrict__ s_dst,
    int M) {
  __shared__ __align__(16) char Xs[TM * 256 * 2];   // 32 KB, frag-order bf16
  const int tid = threadIdx.x;
  const int l = tid & 63;
  const int w = tid >> 6;
  const int lc = l & 15;
  const int lg = l >> 4;
  const int row0 = blockIdx.x * TM;

  // Preload B fragments for this wave's two col-frags.
  s16x8 bfr0[8], bfr1[8];
#pragma unroll
  for (int ks = 0; ks < 8; ++ks) {
    int kb = ks * 4 + lg;
    bfr0[ks] = *(const s16x8*)&Wf[((size_t)kb * F_OUT + w * 16 + lc) * 8];
    bfr1[ks] = *(const s16x8*)&Wf[((size_t)kb * F_OUT + 64 + w * 16 + lc) * 8];
  }

  // Stage X tile: fp32 -> bf16, frag order, XOR swizzle ^((kb&7)<<4).
#pragma unroll
  for (int it = 0; it < 8; ++it) {
    int idx = it * 256 + tid;          // 0..2047 -> (r, kb)
    int r = idx >> 5, kb = idx & 31;
    f32x4 v0 = {0.f, 0.f, 0.f, 0.f}, v1 = {0.f, 0.f, 0.f, 0.f};
    if (row0 + r < M) {
      const f32x4* p = (const f32x4*)&X[(size_t)(row0 + r) * F_IN + kb * 8];
      v0 = p[0]; v1 = p[1];
    }
    union { s16x8 v; ushort u[8]; } t;
    t.u[0] = f2bf(v0[0]); t.u[1] = f2bf(v0[1]); t.u[2] = f2bf(v0[2]); t.u[3] = f2bf(v0[3]);
    t.u[4] = f2bf(v1[0]); t.u[5] = f2bf(v1[1]); t.u[6] = f2bf(v1[2]); t.u[7] = f2bf(v1[3]);
    int byte = ((r >> 4) * 8192) + kb * 256 + (r & 15) * 16;
    byte ^= (kb & 7) << 4;
    *(s16x8*)(Xs + byte) = t.v;
  }
  __syncthreads();

  f32x4 acc0[4] = {}, acc1[4] = {}, accS[4] = {};
#pragma unroll
  for (int ks = 0; ks < 8; ++ks) {
    int kb = ks * 4 + lg;
    int ab = kb * 256 + lc * 16;
    ab ^= (kb & 7) << 4;
    s16x8 bS;
    if (w == 0) bS = *(const s16x8*)&Wfs[((size_t)kb * 16 + lc) * 8];
#pragma unroll
    for (int rf = 0; rf < 4; ++rf) {
      s16x8 af = *(const s16x8*)(Xs + rf * 8192 + ab);
      acc0[rf] = __builtin_amdgcn_mfma_f32_16x16x32_bf16(af, bfr0[ks], acc0[rf], 0, 0, 0);
      acc1[rf] = __builtin_amdgcn_mfma_f32_16x16x32_bf16(af, bfr1[ks], acc1[rf], 0, 0, 0);
      if (w == 0)
        accS[rf] = __builtin_amdgcn_mfma_f32_16x16x32_bf16(af, bS, accS[rf], 0, 0, 0);
    }
  }

  // Hb store: u32 slot s = w*16+lc holds cols (s, s+64) as (lo, hi) bf16.
#pragma unroll
  for (int rf = 0; rf < 4; ++rf) {
#pragma unroll
    for (int q = 0; q < 4; ++q) {
      int rg = row0 + rf * 16 + lg * 4 + q;
      if (rg < M)
        Hb32[(size_t)rg * 64 + w * 16 + lc] = pk2bf(acc0[rf][q], acc1[rf][q]);
    }
  }

  // s_src (lc==0) / s_dst (lc==1) straight from accS.
  if (w == 0 && lc < 2) {
    float* sout = (lc == 0) ? s_src : s_dst;
#pragma unroll
    for (int rf = 0; rf < 4; ++rf) {
#pragma unroll
      for (int q = 0; q < 4; ++q) {
        int rg = row0 + rf * 16 + lg * 4 + q;
        if (rg < M) sout[rg] = accS[rf][q];
      }
    }
  }
}

// ---------------------------------------------------------------------------
// CSR build, atomic-free scatter:
// hist: deg histogram AND per-edge rank (the atomicAdd return), 4 edges/thread.
// ---------------------------------------------------------------------------
__global__ __launch_bounds__(256) void hist_rank_kernel(
    const int* __restrict__ src, int* __restrict__ deg,
    int* __restrict__ rank, int E) {
  int e0 = (blockIdx.x * 256 + threadIdx.x) * 4;
  if (e0 + 4 <= E) {
    int4 s4 = *(const int4*)(src + e0);
    int4 r4;
    r4.x = atomicAdd(&deg[s4.x], 1);
    r4.y = atomicAdd(&deg[s4.y], 1);
    r4.z = atomicAdd(&deg[s4.z], 1);
    r4.w = atomicAdd(&deg[s4.w], 1);
    *(int4*)(rank + e0) = r4;
  } else {
    for (int e = e0; e < E; ++e) rank[e] = atomicAdd(&deg[src[e]], 1);
  }
}

__global__ void block_sums_kernel(const int* __restrict__ deg, int* __restrict__ bs, int N) {
  int i = blockIdx.x * 256 + threadIdx.x;
  int v = (i < N) ? deg[i] : 0;
  int lane = threadIdx.x & 63, w = threadIdx.x >> 6;
#pragma unroll
  for (int d = 32; d >= 1; d >>= 1) v += __shfl_down(v, d);
  __shared__ int wsum[4];
  if (lane == 0) wsum[w] = v;
  __syncthreads();
  if (threadIdx.x == 0) bs[blockIdx.x] = wsum[0] + wsum[1] + wsum[2] + wsum[3];
}

__global__ void scan_blocksums_kernel(int* __restrict__ bs, int n) {
  int tid = threadIdx.x;
  int v = (tid < n) ? bs[tid] : 0;
  int lane = tid & 63, w = tid >> 6;
  int iv = v;
#pragma unroll
  for (int d = 1; d < 64; d <<= 1) {
    int t = __shfl_up(iv, d);
    if (lane >= d) iv += t;
  }
  __shared__ int wsum[4];
  if (lane == 63) wsum[w] = iv;
  __syncthreads();
  int off = 0;
  for (int x = 0; x < w; ++x) off += wsum[x];
  int excl = off + iv - v;
  if (tid < n) bs[tid] = excl;
}

__global__ void scan_deg_kernel(const int* __restrict__ deg, const int* __restrict__ bsum,
                                int* __restrict__ rowptr, int N, int E) {
  int i = blockIdx.x * 256 + threadIdx.x;
  int v = (i < N) ? deg[i] : 0;
  int lane = threadIdx.x & 63, w = threadIdx.x >> 6;
  int iv = v;
#pragma unroll
  for (int d = 1; d < 64; d <<= 1) {
    int t = __shfl_up(iv, d);
    if (lane >= d) iv += t;
  }
  __shared__ int wsum[4];
  if (lane == 63) wsum[w] = iv;
  __syncthreads();
  int off = bsum[blockIdx.x];
  for (int x = 0; x < w; ++x) off += wsum[x];
  int excl = off + iv - v;
  if (i < N) rowptr[i] = excl;
  if (i == N - 1) rowptr[N] = E;
}

// ---------------------------------------------------------------------------
// Atomic-free scatter: colidx[rowptr[s] + rank[e]] = dst[e]. Pure streaming
// reads (int4) + scattered 4B writes; BW-bound, no serialization.
// ---------------------------------------------------------------------------
__global__ __launch_bounds__(256) void scatter_kernel(
    const int* __restrict__ src, const int* __restrict__ dst,
    const int* __restrict__ rank, const int* __restrict__ rowptr,
    int* __restrict__ colidx, int E) {
  int e0 = (blockIdx.x * 256 + threadIdx.x) * 4;
  if (e0 + 4 <= E) {
    int4 s4 = *(const int4*)(src + e0);
    int4 d4 = *(const int4*)(dst + e0);
    int4 r4 = *(const int4*)(rank + e0);
    colidx[rowptr[s4.x] + r4.x] = d4.x;
    colidx[rowptr[s4.y] + r4.y] = d4.y;
    colidx[rowptr[s4.z] + r4.z] = d4.z;
    colidx[rowptr[s4.w] + r4.w] = d4.w;
  } else {
    for (int e = e0; e < E; ++e) colidx[rowptr[src[e]] + rank[e]] = dst[e];
  }
}

// ---------------------------------------------------------------------------
// Aggregation v2: one wave per node (4/block). Lane-parallel softmax per
// <=64-edge chunk, then 4-edge-parallel gather: wave = 4 groups x 16 lanes,
// group g takes edge k+g, lane lc loads uint4 = slots lc*4..lc*4+3 (16B).
// Hand-unrolled x2 -> 8 edges/iter. Final shfl_xor(16,32) group-reduce.
// Slot s packs cols (s, s+64) as (lo,hi) bf16 per Hb32 layout.
// ---------------------------------------------------------------------------
__global__ __launch_bounds__(256) void aggregate_kernel(
    const uint* __restrict__ H32, const float* __restrict__ s_src,
    const float* __restrict__ s_dst, const int* __restrict__ rowptr,
    const int* __restrict__ colidx, float* __restrict__ out, int M) {
  int node = blockIdx.x * 4 + (threadIdx.x >> 6);
  int l = threadIdx.x & 63;
  if (node >= M) return;
  const int g = l >> 4;       // edge group 0..3
  const int lc = l & 15;      // column lane within group
  int beg = rowptr[node], end = rowptr[node + 1];
  float ssrc = s_src[node];
  float m = -INFINITY, denom = 0.f;
  float acc[8] = {};          // slot t: acc[2t]=lo col lc*4+t, acc[2t+1]=hi col 64+lc*4+t

  for (int base = beg; base < end; base += 64) {
    int cnt = end - base; if (cnt > 64) cnt = 64;
    int jv = 0; float ev = -INFINITY;
    if (l < cnt) {
      jv = colidx[base + l];
      float e = ssrc + s_dst[jv];
      ev = (e > 0.f) ? e : ALPHA * e;
    }
    float cm = ev;
#pragma unroll
    for (int mask = 1; mask < 64; mask <<= 1) cm = fmaxf(cm, __shfl_xor(cm, mask));
    float mn = fmaxf(m, cm);
    float wv = (l < cnt) ? __expf(ev - mn) : 0.f;   // 0 for lanes >= cnt
    float sw = wv;
#pragma unroll
    for (int mask = 1; mask < 64; mask <<= 1) sw += __shfl_xor(sw, mask);
    float resc = __expf(m - mn);   // first chunk: exp(-inf) = 0
    denom = denom * resc + sw;
#pragma unroll
    for (int t = 0; t < 8; ++t) acc[t] *= resc;
    m = mn;

    // 8 edges per iteration: groups cover k+g and k+4+g. Lanes >= cnt hold
    // (jv=0, wv=0) so out-of-range edges contribute nothing (branchless).
    for (int k = 0; k < cnt; k += 8) {
      int k0 = k + g, k1 = k + 4 + g;
      int j0 = __shfl(jv, k0);
      int j1 = (k1 < 64) ? __shfl(jv, k1) : 0;
      float w0 = __shfl(wv, k0);
      float w1 = (k1 < 64) ? __shfl(wv, k1) : 0.f;
      uint4 u0 = *(const uint4*)(H32 + ((size_t)(uint)j0 << 6) + lc * 4);
      uint4 u1 = *(const uint4*)(H32 + ((size_t)(uint)j1 << 6) + lc * 4);
      acc[0] += w0 * bflo(u0.x) + w1 * bflo(u1.x);
      acc[1] += w0 * bfhi(u0.x) + w1 * bfhi(u1.x);
      acc[2] += w0 * bflo(u0.y) + w1 * bflo(u1.y);
      acc[3] += w0 * bfhi(u0.y) + w1 * bfhi(u1.y);
      acc[4] += w0 * bflo(u0.z) + w1 * bflo(u1.z);
      acc[5] += w0 * bfhi(u0.z) + w1 * bfhi(u1.z);
      acc[6] += w0 * bflo(u0.w) + w1 * bflo(u1.w);
      acc[7] += w0 * bfhi(u0.w) + w1 * bfhi(u1.w);
    }
  }

  // reduce across the 4 edge groups (lanes lc, lc+16, lc+32, lc+48)
#pragma unroll
  for (int t = 0; t < 8; ++t) {
    acc[t] += __shfl_xor(acc[t], 16);
    acc[t] += __shfl_xor(acc[t], 32);
  }
  float inv = (denom > 0.f) ? 1.f / denom : 0.f;
  if (g == 0) {
    float4 v;
    v.x = acc[0] * inv; v.y = acc[2] * inv; v.z = acc[4] * inv; v.w = acc[6] * inv;
    v.x = (v.x > 0.f) ? v.x : __expf(v.x) - 1.f;
    v.y = (v.y > 0.f) ? v.y : __expf(v.y) - 1.f;
    v.z = (v.z > 0.f) ? v.z : __expf(v.z) - 1.f;
    v.w = (v.w > 0.f) ? v.w : __expf(v.w) - 1.f;
    *(float4*)&out[(size_t)node * 128 + lc * 4] = v;
  } else if (g == 1) {
    float4 v;
    v.x = acc[1] * inv; v.y = acc[3] * inv; v.z = acc[5] * inv; v.w = acc[7] * inv;
    v.x = (v.x > 0.f) ? v.x : __expf(v.x) - 1.f;
    v.y = (v.y > 0.f) ? v.y : __expf(v.y) - 1.f;
    v.z = (v.z > 0.f) ? v.z : __expf(v.z) - 1.f;
    v.w = (v.w > 0.f) ? v.w : __expf(v.w) - 1.f;
    *(float4*)&out[(size_t)node * 128 + 64 + lc * 4] = v;
  }
}

// ---------------------------------------------------------------------------
extern "C" void kernel_launch(void* const* d_in, const int* in_sizes, int n_in,
                              void* d_out, int out_size, void* d_ws, size_t ws_size,
                              hipStream_t stream) {
  const float* x    = (const float*)d_in[0];
  const float* W    = (const float*)d_in[1];
  const float* avec = (const float*)d_in[2];
  const int*   edge = (const int*)d_in[3];

  const int M = in_sizes[0] / F_IN;   // 50000
  const int E = in_sizes[3] / 2;      // 800000
  const int* src = edge;
  const int* dst = edge + E;
  float* out = (float*)d_out;

  char* ws = (char*)d_ws;
  uint*   Hb32  = (uint*)ws;   ws += (size_t)M * 64 * sizeof(uint);
  ushort* Wf    = (ushort*)ws; ws += (size_t)32 * F_OUT * 8 * sizeof(ushort);
  ushort* Wfs   = (ushort*)ws; ws += (size_t)32 * 16 * 8 * sizeof(ushort);
  float* s_src  = (float*)ws;  ws += (size_t)M * sizeof(float);
  float* s_dst  = (float*)ws;  ws += (size_t)M * sizeof(float);
  int*   deg    = (int*)ws;    ws += (size_t)M * sizeof(int);
  int*   rowptr = (int*)ws;    ws += (size_t)(M + 1) * sizeof(int);
  int*   rank   = (int*)ws;    ws += (size_t)E * sizeof(int);
  int*   colidx = (int*)ws;    ws += (size_t)E * sizeof(int);
  int*   bsums  = (int*)ws;

  const int NS = (M + 255) / 256;
  const int n4 = M / 4;                                // deg zero (M % 4 == 0)
  const int E4 = (E + 1023) / 1024;                    // blocks for 4-edge/thread

  zero_kernel<<<(n4 + 255) / 256, 256, 0, stream>>>((int4*)deg, n4);
  pack_w_kernel<<<16, 256, 0, stream>>>(W, Wf);
  pack_wa_kernel<<<1, 256, 0, stream>>>(W, avec, Wfs);
  gemm_mfma_kernel<<<(M + TM - 1) / TM, 256, 0, stream>>>(x, Wf, Wfs, Hb32, s_src, s_dst, M);
  hist_rank_kernel<<<E4, 256, 0, stream>>>(src, deg, rank, E);
  block_sums_kernel<<<NS, 256, 0, stream>>>(deg, bsums, M);
  scan_blocksums_kernel<<<1, 256, 0, stream>>>(bsums, NS);
  scan_deg_kernel<<<NS, 256, 0, stream>>>(deg, bsums, rowptr, M, E);
  scatter_kernel<<<E4, 256, 0, stream>>>(src, dst, rank, rowptr, colidx, E);
  aggregate_kernel<<<(M + 3) / 4, 256, 0, stream>>>(Hb32, s_src, s_dst, rowptr, colidx, out, M);
}

// Round 10
// 125.876 us; speedup vs baseline: 1.8120x; 1.0306x over previous
//
#include <hip/hip_runtime.h>
#include <hip/hip_bf16.h>
#include <math.h>

#define F_IN   256
#define F_OUT  128
#define ALPHA  0.2f
#define TM     64       // GEMM row tile

typedef __attribute__((ext_vector_type(8))) short s16x8;
typedef __attribute__((ext_vector_type(4))) float f32x4;

__device__ __forceinline__ ushort f2bf(float f) {
  __hip_bfloat16 h = __float2bfloat16(f);
  return *reinterpret_cast<ushort*>(&h);
}
__device__ __forceinline__ uint pk2bf(float lo, float hi) {
  return (uint)f2bf(lo) | ((uint)f2bf(hi) << 16);
}
__device__ __forceinline__ float bflo(uint u) { return __uint_as_float(u << 16); }
__device__ __forceinline__ float bfhi(uint u) { return __uint_as_float(u & 0xffff0000u); }

// ---------------------------------------------------------------------------
// Zero kernel (runtime fillBuffer was 44us for 400KB)
// ---------------------------------------------------------------------------
__global__ __launch_bounds__(256) void zero_kernel(int4* __restrict__ p, int n4) {
  int i = blockIdx.x * 256 + threadIdx.x;
  if (i < n4) p[i] = make_int4(0, 0, 0, 0);
}

// ---------------------------------------------------------------------------
// Fused W packing. Blocks 0..15: Wf (B-frag order bf16); block 16: Wfs
// (wa1|wa2 16-col B-frag tile: col0 = W@a[:128], col1 = W@a[128:], rest 0).
// ---------------------------------------------------------------------------
__global__ __launch_bounds__(256) void pack_all_kernel(
    const float* __restrict__ W, const float* __restrict__ avec,
    ushort* __restrict__ Wf, ushort* __restrict__ Wfs) {
  if (blockIdx.x < 16) {
    int idx = blockIdx.x * 256 + threadIdx.x;   // 4096 fragments-of-8
    int kb = idx >> 7, c = idx & 127;
    union { s16x8 v; ushort u[8]; } t;
#pragma unroll
    for (int j = 0; j < 8; ++j) t.u[j] = f2bf(W[(kb * 8 + j) * F_OUT + c]);
    *(s16x8*)&Wf[(size_t)idx * 8] = t.v;
  } else {
    int k = threadIdx.x;   // 0..255 = K row of W
    float s1 = 0.f, s2 = 0.f;
    for (int c = 0; c < F_OUT; ++c) {
      float wv = W[k * F_OUT + c];
      s1 += wv * avec[c];
      s2 += wv * avec[F_OUT + c];
    }
    int kb = k >> 3, j8 = k & 7;
    ushort b1 = f2bf(s1), b2 = f2bf(s2);
#pragma unroll
    for (int cc = 0; cc < 16; ++cc) {
      ushort v = (cc == 0) ? b1 : (cc == 1) ? b2 : (ushort)0;
      Wfs[((size_t)kb * 16 + cc) * 8 + j8] = v;
    }
  }
}

// ---------------------------------------------------------------------------
// MFMA GEMM: Hb32[M][64] u32 = packed bf16 cols (l, l+64) of H = bf16(X) @ W.
// 64-row tile, 256 threads = 4 waves; wave w owns col-frags j=w, j=w+4.
// B-frags preloaded to registers; A staged in LDS (frag order, XOR swizzle).
// Staging is two explicit phases of 8 unconditional row-clamped 16B loads
// issued back-to-back (guaranteed MLP; the old per-iter `if(row<M) load`
// serialized 8 HBM round-trips -> 40us latency-bound kernel).
// s_src/s_dst via 9th B-frag (wa cols) on wave 0.
// ---------------------------------------------------------------------------
__global__ __launch_bounds__(256) void gemm_mfma_kernel(
    const float* __restrict__ X, const ushort* __restrict__ Wf,
    const ushort* __restrict__ Wfs,
    uint* __restrict__ Hb32, float* __restrict__ s_src, float* __restrict__ s_dst,
    int M) {
  __shared__ __align__(16) char Xs[TM * 256 * 2];   // 32 KB, frag-order bf16
  const int tid = threadIdx.x;
  const int l = tid & 63;
  const int w = tid >> 6;
  const int lc = l & 15;
  const int lg = l >> 4;
  const int row0 = blockIdx.x * TM;

  // Preload B fragments for this wave's two col-frags.
  s16x8 bfr0[8], bfr1[8];
#pragma unroll
  for (int ks = 0; ks < 8; ++ks) {
    int kb = ks * 4 + lg;
    bfr0[ks] = *(const s16x8*)&Wf[((size_t)kb * F_OUT + w * 16 + lc) * 8];
    bfr1[ks] = *(const s16x8*)&Wf[((size_t)kb * F_OUT + 64 + w * 16 + lc) * 8];
  }

  // Stage X tile: fp32 -> bf16, frag order, XOR swizzle ^((kb&7)<<4).
#pragma unroll
  for (int half = 0; half < 2; ++half) {
    f32x4 v[8];
    // phase A: issue 8 x 16B loads, no branches (row clamped; OOB rows stage
    // row M-1's data which is never stored)
#pragma unroll
    for (int u = 0; u < 4; ++u) {
      int idx = (half * 4 + u) * 256 + tid;    // 0..2047 -> (r, kb)
      int r = idx >> 5, kb = idx & 31;
      int gr = row0 + r; gr = (gr < M) ? gr : (M - 1);
      const f32x4* p = (const f32x4*)&X[(size_t)gr * F_IN + kb * 8];
      v[u * 2]     = p[0];
      v[u * 2 + 1] = p[1];
    }
    // phase B: convert + swizzled LDS write
#pragma unroll
    for (int u = 0; u < 4; ++u) {
      int idx = (half * 4 + u) * 256 + tid;
      int r = idx >> 5, kb = idx & 31;
      f32x4 v0 = v[u * 2], v1 = v[u * 2 + 1];
      union { s16x8 vv; ushort uu[8]; } t;
      t.uu[0] = f2bf(v0[0]); t.uu[1] = f2bf(v0[1]); t.uu[2] = f2bf(v0[2]); t.uu[3] = f2bf(v0[3]);
      t.uu[4] = f2bf(v1[0]); t.uu[5] = f2bf(v1[1]); t.uu[6] = f2bf(v1[2]); t.uu[7] = f2bf(v1[3]);
      int byte = ((r >> 4) * 8192) + kb * 256 + (r & 15) * 16;
      byte ^= (kb & 7) << 4;
      *(s16x8*)(Xs + byte) = t.vv;
    }
  }
  __syncthreads();

  f32x4 acc0[4] = {}, acc1[4] = {}, accS[4] = {};
#pragma unroll
  for (int ks = 0; ks < 8; ++ks) {
    int kb = ks * 4 + lg;
    int ab = kb * 256 + lc * 16;
    ab ^= (kb & 7) << 4;
    s16x8 bS;
    if (w == 0) bS = *(const s16x8*)&Wfs[((size_t)kb * 16 + lc) * 8];
#pragma unroll
    for (int rf = 0; rf < 4; ++rf) {
      s16x8 af = *(const s16x8*)(Xs + rf * 8192 + ab);
      acc0[rf] = __builtin_amdgcn_mfma_f32_16x16x32_bf16(af, bfr0[ks], acc0[rf], 0, 0, 0);
      acc1[rf] = __builtin_amdgcn_mfma_f32_16x16x32_bf16(af, bfr1[ks], acc1[rf], 0, 0, 0);
      if (w == 0)
        accS[rf] = __builtin_amdgcn_mfma_f32_16x16x32_bf16(af, bS, accS[rf], 0, 0, 0);
    }
  }

  // Hb store: u32 slot s = w*16+lc holds cols (s, s+64) as (lo, hi) bf16.
#pragma unroll
  for (int rf = 0; rf < 4; ++rf) {
#pragma unroll
    for (int q = 0; q < 4; ++q) {
      int rg = row0 + rf * 16 + lg * 4 + q;
      if (rg < M)
        Hb32[(size_t)rg * 64 + w * 16 + lc] = pk2bf(acc0[rf][q], acc1[rf][q]);
    }
  }

  // s_src (lc==0) / s_dst (lc==1) straight from accS.
  if (w == 0 && lc < 2) {
    float* sout = (lc == 0) ? s_src : s_dst;
#pragma unroll
    for (int rf = 0; rf < 4; ++rf) {
#pragma unroll
      for (int q = 0; q < 4; ++q) {
        int rg = row0 + rf * 16 + lg * 4 + q;
        if (rg < M) sout[rg] = accS[rf][q];
      }
    }
  }
}

// ---------------------------------------------------------------------------
// CSR build, atomic-free scatter:
// hist: deg histogram AND per-edge rank (the atomicAdd return), 4 edges/thread.
// ---------------------------------------------------------------------------
__global__ __launch_bounds__(256) void hist_rank_kernel(
    const int* __restrict__ src, int* __restrict__ deg,
    int* __restrict__ rank, int E) {
  int e0 = (blockIdx.x * 256 + threadIdx.x) * 4;
  if (e0 + 4 <= E) {
    int4 s4 = *(const int4*)(src + e0);
    int4 r4;
    r4.x = atomicAdd(&deg[s4.x], 1);
    r4.y = atomicAdd(&deg[s4.y], 1);
    r4.z = atomicAdd(&deg[s4.z], 1);
    r4.w = atomicAdd(&deg[s4.w], 1);
    *(int4*)(rank + e0) = r4;
  } else {
    for (int e = e0; e < E; ++e) rank[e] = atomicAdd(&deg[src[e]], 1);
  }
}

__global__ void block_sums_kernel(const int* __restrict__ deg, int* __restrict__ bs, int N) {
  int i = blockIdx.x * 256 + threadIdx.x;
  int v = (i < N) ? deg[i] : 0;
  int lane = threadIdx.x & 63, w = threadIdx.x >> 6;
#pragma unroll
  for (int d = 32; d >= 1; d >>= 1) v += __shfl_down(v, d);
  __shared__ int wsum[4];
  if (lane == 0) wsum[w] = v;
  __syncthreads();
  if (threadIdx.x == 0) bs[blockIdx.x] = wsum[0] + wsum[1] + wsum[2] + wsum[3];
}

__global__ void scan_blocksums_kernel(int* __restrict__ bs, int n) {
  int tid = threadIdx.x;
  int v = (tid < n) ? bs[tid] : 0;
  int lane = tid & 63, w = tid >> 6;
  int iv = v;
#pragma unroll
  for (int d = 1; d < 64; d <<= 1) {
    int t = __shfl_up(iv, d);
    if (lane >= d) iv += t;
  }
  __shared__ int wsum[4];
  if (lane == 63) wsum[w] = iv;
  __syncthreads();
  int off = 0;
  for (int x = 0; x < w; ++x) off += wsum[x];
  int excl = off + iv - v;
  if (tid < n) bs[tid] = excl;
}

__global__ void scan_deg_kernel(const int* __restrict__ deg, const int* __restrict__ bsum,
                                int* __restrict__ rowptr, int N, int E) {
  int i = blockIdx.x * 256 + threadIdx.x;
  int v = (i < N) ? deg[i] : 0;
  int lane = threadIdx.x & 63, w = threadIdx.x >> 6;
  int iv = v;
#pragma unroll
  for (int d = 1; d < 64; d <<= 1) {
    int t = __shfl_up(iv, d);
    if (lane >= d) iv += t;
  }
  __shared__ int wsum[4];
  if (lane == 63) wsum[w] = iv;
  __syncthreads();
  int off = bsum[blockIdx.x];
  for (int x = 0; x < w; ++x) off += wsum[x];
  int excl = off + iv - v;
  if (i < N) rowptr[i] = excl;
  if (i == N - 1) rowptr[N] = E;
}

// ---------------------------------------------------------------------------
// Atomic-free scatter: colidx[rowptr[s] + rank[e]] = dst[e]. Pure streaming
// reads (int4) + scattered 4B writes; BW-bound, no serialization.
// ---------------------------------------------------------------------------
__global__ __launch_bounds__(256) void scatter_kernel(
    const int* __restrict__ src, const int* __restrict__ dst,
    const int* __restrict__ rank, const int* __restrict__ rowptr,
    int* __restrict__ colidx, int E) {
  int e0 = (blockIdx.x * 256 + threadIdx.x) * 4;
  if (e0 + 4 <= E) {
    int4 s4 = *(const int4*)(src + e0);
    int4 d4 = *(const int4*)(dst + e0);
    int4 r4 = *(const int4*)(rank + e0);
    colidx[rowptr[s4.x] + r4.x] = d4.x;
    colidx[rowptr[s4.y] + r4.y] = d4.y;
    colidx[rowptr[s4.z] + r4.z] = d4.z;
    colidx[rowptr[s4.w] + r4.w] = d4.w;
  } else {
    for (int e = e0; e < E; ++e) colidx[rowptr[src[e]] + rank[e]] = dst[e];
  }
}

// ---------------------------------------------------------------------------
// Aggregation v2: one wave per node (4/block). Lane-parallel softmax per
// <=64-edge chunk, then 4-edge-parallel gather: wave = 4 groups x 16 lanes,
// group g takes edge k+g, lane lc loads uint4 = slots lc*4..lc*4+3 (16B).
// Hand-unrolled x2 -> 8 edges/iter. Final shfl_xor(16,32) group-reduce.
// Slot s packs cols (s, s+64) as (lo,hi) bf16 per Hb32 layout.
// ---------------------------------------------------------------------------
__global__ __launch_bounds__(256) void aggregate_kernel(
    const uint* __restrict__ H32, const float* __restrict__ s_src,
    const float* __restrict__ s_dst, const int* __restrict__ rowptr,
    const int* __restrict__ colidx, float* __restrict__ out, int M) {
  int node = blockIdx.x * 4 + (threadIdx.x >> 6);
  int l = threadIdx.x & 63;
  if (node >= M) return;
  const int g = l >> 4;       // edge group 0..3
  const int lc = l & 15;      // column lane within group
  int beg = rowptr[node], end = rowptr[node + 1];
  float ssrc = s_src[node];
  float m = -INFINITY, denom = 0.f;
  float acc[8] = {};          // slot t: acc[2t]=lo col lc*4+t, acc[2t+1]=hi col 64+lc*4+t

  for (int base = beg; base < end; base += 64) {
    int cnt = end - base; if (cnt > 64) cnt = 64;
    int jv = 0; float ev = -INFINITY;
    if (l < cnt) {
      jv = colidx[base + l];
      float e = ssrc + s_dst[jv];
      ev = (e > 0.f) ? e : ALPHA * e;
    }
    float cm = ev;
#pragma unroll
    for (int mask = 1; mask < 64; mask <<= 1) cm = fmaxf(cm, __shfl_xor(cm, mask));
    float mn = fmaxf(m, cm);
    float wv = (l < cnt) ? __expf(ev - mn) : 0.f;   // 0 for lanes >= cnt
    float sw = wv;
#pragma unroll
    for (int mask = 1; mask < 64; mask <<= 1) sw += __shfl_xor(sw, mask);
    float resc = __expf(m - mn);   // first chunk: exp(-inf) = 0
    denom = denom * resc + sw;
#pragma unroll
    for (int t = 0; t < 8; ++t) acc[t] *= resc;
    m = mn;

    // 8 edges per iteration: groups cover k+g and k+4+g. Lanes >= cnt hold
    // (jv=0, wv=0) so out-of-range edges contribute nothing (branchless).
    for (int k = 0; k < cnt; k += 8) {
      int k0 = k + g, k1 = k + 4 + g;
      int j0 = __shfl(jv, k0);
      int j1 = (k1 < 64) ? __shfl(jv, k1) : 0;
      float w0 = __shfl(wv, k0);
      float w1 = (k1 < 64) ? __shfl(wv, k1) : 0.f;
      uint4 u0 = *(const uint4*)(H32 + ((size_t)(uint)j0 << 6) + lc * 4);
      uint4 u1 = *(const uint4*)(H32 + ((size_t)(uint)j1 << 6) + lc * 4);
      acc[0] += w0 * bflo(u0.x) + w1 * bflo(u1.x);
      acc[1] += w0 * bfhi(u0.x) + w1 * bfhi(u1.x);
      acc[2] += w0 * bflo(u0.y) + w1 * bflo(u1.y);
      acc[3] += w0 * bfhi(u0.y) + w1 * bfhi(u1.y);
      acc[4] += w0 * bflo(u0.z) + w1 * bflo(u1.z);
      acc[5] += w0 * bfhi(u0.z) + w1 * bfhi(u1.z);
      acc[6] += w0 * bflo(u0.w) + w1 * bflo(u1.w);
      acc[7] += w0 * bfhi(u0.w) + w1 * bfhi(u1.w);
    }
  }

  // reduce across the 4 edge groups (lanes lc, lc+16, lc+32, lc+48)
#pragma unroll
  for (int t = 0; t < 8; ++t) {
    acc[t] += __shfl_xor(acc[t], 16);
    acc[t] += __shfl_xor(acc[t], 32);
  }
  float inv = (denom > 0.f) ? 1.f / denom : 0.f;
  if (g == 0) {
    float4 v;
    v.x = acc[0] * inv; v.y = acc[2] * inv; v.z = acc[4] * inv; v.w = acc[6] * inv;
    v.x = (v.x > 0.f) ? v.x : __expf(v.x) - 1.f;
    v.y = (v.y > 0.f) ? v.y : __expf(v.y) - 1.f;
    v.z = (v.z > 0.f) ? v.z : __expf(v.z) - 1.f;
    v.w = (v.w > 0.f) ? v.w : __expf(v.w) - 1.f;
    *(float4*)&out[(size_t)node * 128 + lc * 4] = v;
  } else if (g == 1) {
    float4 v;
    v.x = acc[1] * inv; v.y = acc[3] * inv; v.z = acc[5] * inv; v.w = acc[7] * inv;
    v.x = (v.x > 0.f) ? v.x : __expf(v.x) - 1.f;
    v.y = (v.y > 0.f) ? v.y : __expf(v.y) - 1.f;
    v.z = (v.z > 0.f) ? v.z : __expf(v.z) - 1.f;
    v.w = (v.w > 0.f) ? v.w : __expf(v.w) - 1.f;
    *(float4*)&out[(size_t)node * 128 + 64 + lc * 4] = v;
  }
}

// ---------------------------------------------------------------------------
extern "C" void kernel_launch(void* const* d_in, const int* in_sizes, int n_in,
                              void* d_out, int out_size, void* d_ws, size_t ws_size,
                              hipStream_t stream) {
  const float* x    = (const float*)d_in[0];
  const float* W    = (const float*)d_in[1];
  const float* avec = (const float*)d_in[2];
  const int*   edge = (const int*)d_in[3];

  const int M = in_sizes[0] / F_IN;   // 50000
  const int E = in_sizes[3] / 2;      // 800000
  const int* src = edge;
  const int* dst = edge + E;
  float* out = (float*)d_out;

  char* ws = (char*)d_ws;
  uint*   Hb32  = (uint*)ws;   ws += (size_t)M * 64 * sizeof(uint);
  ushort* Wf    = (ushort*)ws; ws += (size_t)32 * F_OUT * 8 * sizeof(ushort);
  ushort* Wfs   = (ushort*)ws; ws += (size_t)32 * 16 * 8 * sizeof(ushort);
  float* s_src  = (float*)ws;  ws += (size_t)M * sizeof(float);
  float* s_dst  = (float*)ws;  ws += (size_t)M * sizeof(float);
  int*   deg    = (int*)ws;    ws += (size_t)M * sizeof(int);
  int*   rowptr = (int*)ws;    ws += (size_t)(M + 1) * sizeof(int);
  int*   rank   = (int*)ws;    ws += (size_t)E * sizeof(int);
  int*   colidx = (int*)ws;    ws += (size_t)E * sizeof(int);
  int*   bsums  = (int*)ws;

  const int NS = (M + 255) / 256;
  const int n4 = M / 4;                                // deg zero (M % 4 == 0)
  const int E4 = (E + 1023) / 1024;                    // blocks for 4-edge/thread

  zero_kernel<<<(n4 + 255) / 256, 256, 0, stream>>>((int4*)deg, n4);
  pack_all_kernel<<<17, 256, 0, stream>>>(W, avec, Wf, Wfs);
  gemm_mfma_kernel<<<(M + TM - 1) / TM, 256, 0, stream>>>(x, Wf, Wfs, Hb32, s_src, s_dst, M);
  hist_rank_kernel<<<E4, 256, 0, stream>>>(src, deg, rank, E);
  block_sums_kernel<<<NS, 256, 0, stream>>>(deg, bsums, M);
  scan_blocksums_kernel<<<1, 256, 0, stream>>>(bsums, NS);
  scan_deg_kernel<<<NS, 256, 0, stream>>>(deg, bsums, rowptr, M, E);
  scatter_kernel<<<E4, 256, 0, stream>>>(src, dst, rank, rowptr, colidx, E);
  aggregate_kernel<<<(M + 3) / 4, 256, 0, stream>>>(Hb32, s_src, s_dst, rowptr, colidx, out, M);
}

// Round 12
// 111.745 us; speedup vs baseline: 2.0411x; 1.1265x over previous
//
#include <hip/hip_runtime.h>
#include <hip/hip_bf16.h>
#include <math.h>

#define F_IN   256
#define F_OUT  128
#define ALPHA  0.2f
#define TM     64       // GEMM row tile

typedef __attribute__((ext_vector_type(8))) short s16x8;
typedef __attribute__((ext_vector_type(4))) float f32x4;

__device__ __forceinline__ ushort f2bf(float f) {
  __hip_bfloat16 h = __float2bfloat16(f);
  return *reinterpret_cast<ushort*>(&h);
}
__device__ __forceinline__ uint pk2bf(float lo, float hi) {
  return (uint)f2bf(lo) | ((uint)f2bf(hi) << 16);
}
__device__ __forceinline__ float bflo(uint u) { return __uint_as_float(u << 16); }
__device__ __forceinline__ float bfhi(uint u) { return __uint_as_float(u & 0xffff0000u); }

// ---------------------------------------------------------------------------
// Prep: blocks [0,ZB): zero deg (int4); [ZB,ZB+16): pack Wf; ZB+16: pack Wfs.
// All partitions independent.
// ---------------------------------------------------------------------------
__global__ __launch_bounds__(256) void prep_kernel(
    const float* __restrict__ W, const float* __restrict__ avec,
    ushort* __restrict__ Wf, ushort* __restrict__ Wfs,
    int4* __restrict__ deg4, int n4, int ZB) {
  int b = blockIdx.x;
  if (b < ZB) {
    int i = b * 256 + threadIdx.x;
    if (i < n4) deg4[i] = make_int4(0, 0, 0, 0);
  } else if (b < ZB + 16) {
    int idx = (b - ZB) * 256 + threadIdx.x;   // 4096 fragments-of-8
    int kb = idx >> 7, c = idx & 127;
    union { s16x8 v; ushort u[8]; } t;
#pragma unroll
    for (int j = 0; j < 8; ++j) t.u[j] = f2bf(W[(kb * 8 + j) * F_OUT + c]);
    *(s16x8*)&Wf[(size_t)idx * 8] = t.v;
  } else {
    int k = threadIdx.x;   // 0..255 = K row of W
    float s1 = 0.f, s2 = 0.f;
    for (int c = 0; c < F_OUT; ++c) {
      float wv = W[k * F_OUT + c];
      s1 += wv * avec[c];
      s2 += wv * avec[F_OUT + c];
    }
    int kb = k >> 3, j8 = k & 7;
    ushort b1 = f2bf(s1), b2 = f2bf(s2);
#pragma unroll
    for (int cc = 0; cc < 16; ++cc) {
      ushort v = (cc == 0) ? b1 : (cc == 1) ? b2 : (ushort)0;
      Wfs[((size_t)kb * 16 + cc) * 8 + j8] = v;
    }
  }
}

// ---------------------------------------------------------------------------
// Fused GEMM + hist (independent work, grid-partitioned):
// blocks [0,G): MFMA GEMM tile (Hb32/s_src/s_dst); blocks [G,..): edge
// histogram + per-edge rank (atomicAdd return), 4 edges/thread.
//
// GEMM: Hb32[M][64] u32 = packed bf16 cols (l, l+64) of H = bf16(X) @ W.
// 64-row tile, 4 waves; wave w owns col-frags j=w, j=w+4. B-frags preloaded
// to registers; A staged in LDS (frag order, XOR swizzle ^((kb&7)<<4)),
// two-phase (8 unconditional row-clamped 16B loads, then convert+write).
// s_src/s_dst via 9th B-frag (wa cols) on wave 0.
// ---------------------------------------------------------------------------
__global__ __launch_bounds__(256) void gemm_hist_kernel(
    const float* __restrict__ X, const ushort* __restrict__ Wf,
    const ushort* __restrict__ Wfs,
    uint* __restrict__ Hb32, float* __restrict__ s_src, float* __restrict__ s_dst,
    int M, int G,
    const int* __restrict__ src, int* __restrict__ deg,
    int* __restrict__ rank, int E) {
  __shared__ __align__(16) char Xs[TM * 256 * 2];   // 32 KB, frag-order bf16
  const int tid = threadIdx.x;

  if (blockIdx.x >= G) {
    // ---- hist partition ----
    int e0 = ((blockIdx.x - G) * 256 + tid) * 4;
    if (e0 + 4 <= E) {
      int4 s4 = *(const int4*)(src + e0);
      int4 r4;
      r4.x = atomicAdd(&deg[s4.x], 1);
      r4.y = atomicAdd(&deg[s4.y], 1);
      r4.z = atomicAdd(&deg[s4.z], 1);
      r4.w = atomicAdd(&deg[s4.w], 1);
      *(int4*)(rank + e0) = r4;
    } else {
      for (int e = e0; e < E; ++e) rank[e] = atomicAdd(&deg[src[e]], 1);
    }
    return;
  }

  // ---- GEMM partition ----
  const int l = tid & 63;
  const int w = tid >> 6;
  const int lc = l & 15;
  const int lg = l >> 4;
  const int row0 = blockIdx.x * TM;

  // Preload B fragments for this wave's two col-frags.
  s16x8 bfr0[8], bfr1[8];
#pragma unroll
  for (int ks = 0; ks < 8; ++ks) {
    int kb = ks * 4 + lg;
    bfr0[ks] = *(const s16x8*)&Wf[((size_t)kb * F_OUT + w * 16 + lc) * 8];
    bfr1[ks] = *(const s16x8*)&Wf[((size_t)kb * F_OUT + 64 + w * 16 + lc) * 8];
  }

  // Stage X tile: fp32 -> bf16, frag order, XOR swizzle.
#pragma unroll
  for (int half = 0; half < 2; ++half) {
    f32x4 v[8];
#pragma unroll
    for (int u = 0; u < 4; ++u) {
      int idx = (half * 4 + u) * 256 + tid;    // 0..2047 -> (r, kb)
      int r = idx >> 5, kb = idx & 31;
      int gr = row0 + r; gr = (gr < M) ? gr : (M - 1);
      const f32x4* p = (const f32x4*)&X[(size_t)gr * F_IN + kb * 8];
      v[u * 2]     = p[0];
      v[u * 2 + 1] = p[1];
    }
#pragma unroll
    for (int u = 0; u < 4; ++u) {
      int idx = (half * 4 + u) * 256 + tid;
      int r = idx >> 5, kb = idx & 31;
      f32x4 v0 = v[u * 2], v1 = v[u * 2 + 1];
      union { s16x8 vv; ushort uu[8]; } t;
      t.uu[0] = f2bf(v0[0]); t.uu[1] = f2bf(v0[1]); t.uu[2] = f2bf(v0[2]); t.uu[3] = f2bf(v0[3]);
      t.uu[4] = f2bf(v1[0]); t.uu[5] = f2bf(v1[1]); t.uu[6] = f2bf(v1[2]); t.uu[7] = f2bf(v1[3]);
      int byte = ((r >> 4) * 8192) + kb * 256 + (r & 15) * 16;
      byte ^= (kb & 7) << 4;
      *(s16x8*)(Xs + byte) = t.vv;
    }
  }
  __syncthreads();

  f32x4 acc0[4] = {}, acc1[4] = {}, accS[4] = {};
#pragma unroll
  for (int ks = 0; ks < 8; ++ks) {
    int kb = ks * 4 + lg;
    int ab = kb * 256 + lc * 16;
    ab ^= (kb & 7) << 4;
    s16x8 bS;
    if (w == 0) bS = *(const s16x8*)&Wfs[((size_t)kb * 16 + lc) * 8];
#pragma unroll
    for (int rf = 0; rf < 4; ++rf) {
      s16x8 af = *(const s16x8*)(Xs + rf * 8192 + ab);
      acc0[rf] = __builtin_amdgcn_mfma_f32_16x16x32_bf16(af, bfr0[ks], acc0[rf], 0, 0, 0);
      acc1[rf] = __builtin_amdgcn_mfma_f32_16x16x32_bf16(af, bfr1[ks], acc1[rf], 0, 0, 0);
      if (w == 0)
        accS[rf] = __builtin_amdgcn_mfma_f32_16x16x32_bf16(af, bS, accS[rf], 0, 0, 0);
    }
  }

  // Hb store: u32 slot s = w*16+lc holds cols (s, s+64) as (lo, hi) bf16.
#pragma unroll
  for (int rf = 0; rf < 4; ++rf) {
#pragma unroll
    for (int q = 0; q < 4; ++q) {
      int rg = row0 + rf * 16 + lg * 4 + q;
      if (rg < M)
        Hb32[(size_t)rg * 64 + w * 16 + lc] = pk2bf(acc0[rf][q], acc1[rf][q]);
    }
  }

  // s_src (lc==0) / s_dst (lc==1) straight from accS.
  if (w == 0 && lc < 2) {
    float* sout = (lc == 0) ? s_src : s_dst;
#pragma unroll
    for (int rf = 0; rf < 4; ++rf) {
#pragma unroll
      for (int q = 0; q < 4; ++q) {
        int rg = row0 + rf * 16 + lg * 4 + q;
        if (rg < M) sout[rg] = accS[rf][q];
      }
    }
  }
}

// ---------------------------------------------------------------------------
// Per-256-chunk sums of deg (input to the fused scan).
// ---------------------------------------------------------------------------
__global__ void block_sums_kernel(const int* __restrict__ deg, int* __restrict__ bs, int N) {
  int i = blockIdx.x * 256 + threadIdx.x;
  int v = (i < N) ? deg[i] : 0;
  int lane = threadIdx.x & 63, w = threadIdx.x >> 6;
#pragma unroll
  for (int d = 32; d >= 1; d >>= 1) v += __shfl_down(v, d);
  __shared__ int wsum[4];
  if (lane == 0) wsum[w] = v;
  __syncthreads();
  if (threadIdx.x == 0) bs[blockIdx.x] = wsum[0] + wsum[1] + wsum[2] + wsum[3];
}

// ---------------------------------------------------------------------------
// Fused scan: every block redundantly exclusive-scans bs[0..NS) (NS<=256,
// ~1us from L2) to get its own offset, then scans its 256 deg values.
// Replaces the separate scan_blocksums kernel (one less launch boundary).
// ---------------------------------------------------------------------------
__global__ void scan_deg_kernel(const int* __restrict__ deg, const int* __restrict__ bs,
                                int* __restrict__ rowptr, int N, int E, int NS) {
  __shared__ int sc[256];
  __shared__ int wsumA[4], wsumB[4];
  int tid = threadIdx.x;
  int lane = tid & 63, w = tid >> 6;

  // exclusive scan of block sums (all blocks do this redundantly)
  int bv = (tid < NS) ? bs[tid] : 0;
  int ibv = bv;
#pragma unroll
  for (int d = 1; d < 64; d <<= 1) {
    int t = __shfl_up(ibv, d);
    if (lane >= d) ibv += t;
  }
  if (lane == 63) wsumA[w] = ibv;
  __syncthreads();
  int boff = 0;
  for (int x = 0; x < w; ++x) boff += wsumA[x];
  sc[tid] = boff + ibv - bv;          // exclusive prefix of bs

  // scan own 256 deg values
  int i = blockIdx.x * 256 + tid;
  int v = (i < N) ? deg[i] : 0;
  int iv = v;
#pragma unroll
  for (int d = 1; d < 64; d <<= 1) {
    int t = __shfl_up(iv, d);
    if (lane >= d) iv += t;
  }
  if (lane == 63) wsumB[w] = iv;
  __syncthreads();                    // covers sc and wsumB
  int off = sc[blockIdx.x];
  for (int x = 0; x < w; ++x) off += wsumB[x];
  int excl = off + iv - v;
  if (i < N) rowptr[i] = excl;
  if (i == N - 1) rowptr[N] = E;
}

// ---------------------------------------------------------------------------
// Atomic-free scatter: colidx[rowptr[s] + rank[e]] = dst[e].
// ---------------------------------------------------------------------------
__global__ __launch_bounds__(256) void scatter_kernel(
    const int* __restrict__ src, const int* __restrict__ dst,
    const int* __restrict__ rank, const int* __restrict__ rowptr,
    int* __restrict__ colidx, int E) {
  int e0 = (blockIdx.x * 256 + threadIdx.x) * 4;
  if (e0 + 4 <= E) {
    int4 s4 = *(const int4*)(src + e0);
    int4 d4 = *(const int4*)(dst + e0);
    int4 r4 = *(const int4*)(rank + e0);
    colidx[rowptr[s4.x] + r4.x] = d4.x;
    colidx[rowptr[s4.y] + r4.y] = d4.y;
    colidx[rowptr[s4.z] + r4.z] = d4.z;
    colidx[rowptr[s4.w] + r4.w] = d4.w;
  } else {
    for (int e = e0; e < E; ++e) colidx[rowptr[src[e]] + rank[e]] = dst[e];
  }
}

// ---------------------------------------------------------------------------
// Aggregation: one wave per node (4/block). Lane-parallel softmax per
// <=64-edge chunk, then 4-edge-parallel gather: wave = 4 groups x 16 lanes,
// group g takes edge k+g, lane lc loads uint4 (16B). 8 edges/iter.
// Final shfl_xor(16,32) group-reduce. Slot s packs cols (s, s+64).
// ---------------------------------------------------------------------------
__global__ __launch_bounds__(256) void aggregate_kernel(
    const uint* __restrict__ H32, const float* __restrict__ s_src,
    const float* __restrict__ s_dst, const int* __restrict__ rowptr,
    const int* __restrict__ colidx, float* __restrict__ out, int M) {
  int node = blockIdx.x * 4 + (threadIdx.x >> 6);
  int l = threadIdx.x & 63;
  if (node >= M) return;
  const int g = l >> 4;       // edge group 0..3
  const int lc = l & 15;      // column lane within group
  int beg = rowptr[node], end = rowptr[node + 1];
  float ssrc = s_src[node];
  float m = -INFINITY, denom = 0.f;
  float acc[8] = {};

  for (int base = beg; base < end; base += 64) {
    int cnt = end - base; if (cnt > 64) cnt = 64;
    int jv = 0; float ev = -INFINITY;
    if (l < cnt) {
      jv = colidx[base + l];
      float e = ssrc + s_dst[jv];
      ev = (e > 0.f) ? e : ALPHA * e;
    }
    float cm = ev;
#pragma unroll
    for (int mask = 1; mask < 64; mask <<= 1) cm = fmaxf(cm, __shfl_xor(cm, mask));
    float mn = fmaxf(m, cm);
    float wv = (l < cnt) ? __expf(ev - mn) : 0.f;
    float sw = wv;
#pragma unroll
    for (int mask = 1; mask < 64; mask <<= 1) sw += __shfl_xor(sw, mask);
    float resc = __expf(m - mn);   // first chunk: exp(-inf) = 0
    denom = denom * resc + sw;
#pragma unroll
    for (int t = 0; t < 8; ++t) acc[t] *= resc;
    m = mn;

    for (int k = 0; k < cnt; k += 8) {
      int k0 = k + g, k1 = k + 4 + g;
      int j0 = __shfl(jv, k0);
      int j1 = (k1 < 64) ? __shfl(jv, k1) : 0;
      float w0 = __shfl(wv, k0);
      float w1 = (k1 < 64) ? __shfl(wv, k1) : 0.f;
      uint4 u0 = *(const uint4*)(H32 + ((size_t)(uint)j0 << 6) + lc * 4);
      uint4 u1 = *(const uint4*)(H32 + ((size_t)(uint)j1 << 6) + lc * 4);
      acc[0] += w0 * bflo(u0.x) + w1 * bflo(u1.x);
      acc[1] += w0 * bfhi(u0.x) + w1 * bfhi(u1.x);
      acc[2] += w0 * bflo(u0.y) + w1 * bflo(u1.y);
      acc[3] += w0 * bfhi(u0.y) + w1 * bfhi(u1.y);
      acc[4] += w0 * bflo(u0.z) + w1 * bflo(u1.z);
      acc[5] += w0 * bfhi(u0.z) + w1 * bfhi(u1.z);
      acc[6] += w0 * bflo(u0.w) + w1 * bflo(u1.w);
      acc[7] += w0 * bfhi(u0.w) + w1 * bfhi(u1.w);
    }
  }

#pragma unroll
  for (int t = 0; t < 8; ++t) {
    acc[t] += __shfl_xor(acc[t], 16);
    acc[t] += __shfl_xor(acc[t], 32);
  }
  float inv = (denom > 0.f) ? 1.f / denom : 0.f;
  if (g == 0) {
    float4 v;
    v.x = acc[0] * inv; v.y = acc[2] * inv; v.z = acc[4] * inv; v.w = acc[6] * inv;
    v.x = (v.x > 0.f) ? v.x : __expf(v.x) - 1.f;
    v.y = (v.y > 0.f) ? v.y : __expf(v.y) - 1.f;
    v.z = (v.z > 0.f) ? v.z : __expf(v.z) - 1.f;
    v.w = (v.w > 0.f) ? v.w : __expf(v.w) - 1.f;
    *(float4*)&out[(size_t)node * 128 + lc * 4] = v;
  } else if (g == 1) {
    float4 v;
    v.x = acc[1] * inv; v.y = acc[3] * inv; v.z = acc[5] * inv; v.w = acc[7] * inv;
    v.x = (v.x > 0.f) ? v.x : __expf(v.x) - 1.f;
    v.y = (v.y > 0.f) ? v.y : __expf(v.y) - 1.f;
    v.z = (v.z > 0.f) ? v.z : __expf(v.z) - 1.f;
    v.w = (v.w > 0.f) ? v.w : __expf(v.w) - 1.f;
    *(float4*)&out[(size_t)node * 128 + 64 + lc * 4] = v;
  }
}

// ---------------------------------------------------------------------------
extern "C" void kernel_launch(void* const* d_in, const int* in_sizes, int n_in,
                              void* d_out, int out_size, void* d_ws, size_t ws_size,
                              hipStream_t stream) {
  const float* x    = (const float*)d_in[0];
  const float* W    = (const float*)d_in[1];
  const float* avec = (const float*)d_in[2];
  const int*   edge = (const int*)d_in[3];

  const int M = in_sizes[0] / F_IN;   // 50000
  const int E = in_sizes[3] / 2;      // 800000
  const int* src = edge;
  const int* dst = edge + E;
  float* out = (float*)d_out;

  char* ws = (char*)d_ws;
  uint*   Hb32  = (uint*)ws;   ws += (size_t)M * 64 * sizeof(uint);
  ushort* Wf    = (ushort*)ws; ws += (size_t)32 * F_OUT * 8 * sizeof(ushort);
  ushort* Wfs   = (ushort*)ws; ws += (size_t)32 * 16 * 8 * sizeof(ushort);
  float* s_src  = (float*)ws;  ws += (size_t)M * sizeof(float);
  float* s_dst  = (float*)ws;  ws += (size_t)M * sizeof(float);
  int*   deg    = (int*)ws;    ws += (size_t)M * sizeof(int);
  int*   rowptr = (int*)ws;    ws += (size_t)(M + 1) * sizeof(int);
  int*   rank   = (int*)ws;    ws += (size_t)E * sizeof(int);
  int*   colidx = (int*)ws;    ws += (size_t)E * sizeof(int);
  int*   bsums  = (int*)ws;

  const int NS = (M + 255) / 256;                      // 196 (<= 256 required)
  const int n4 = M / 4;                                // deg zero (M % 4 == 0)
  const int ZB = (n4 + 255) / 256;                     // zero blocks
  const int E4 = (E + 1023) / 1024;                    // 4-edge/thread blocks
  const int G  = (M + TM - 1) / TM;                    // gemm blocks

  prep_kernel<<<ZB + 17, 256, 0, stream>>>(W, avec, Wf, Wfs, (int4*)deg, n4, ZB);
  gemm_hist_kernel<<<G + E4, 256, 0, stream>>>(x, Wf, Wfs, Hb32, s_src, s_dst,
                                               M, G, src, deg, rank, E);
  block_sums_kernel<<<NS, 256, 0, stream>>>(deg, bsums, M);
  scan_deg_kernel<<<NS, 256, 0, stream>>>(deg, bsums, rowptr, M, E, NS);
  scatter_kernel<<<E4, 256, 0, stream>>>(src, dst, rank, rowptr, colidx, E);
  aggregate_kernel<<<(M + 3) / 4, 256, 0, stream>>>(Hb32, s_src, s_dst, rowptr, colidx, out, M);
}